// Round 1
// baseline (254.267 us; speedup 1.0000x reference)
//
#include <hip/hip_runtime.h>
#include <math.h>

typedef __bf16 bf16;
typedef __bf16 bf16x8 __attribute__((ext_vector_type(8)));
typedef __bf16 bf16x4 __attribute__((ext_vector_type(4)));
typedef __bf16 bf16x2 __attribute__((ext_vector_type(2)));
typedef float f32x4 __attribute__((ext_vector_type(4)));
typedef float f32x2 __attribute__((ext_vector_type(2)));

#define AS1 __attribute__((address_space(1)))
#define AS3 __attribute__((address_space(3)))

static __device__ __forceinline__ f32x4 mfma16(bf16x8 a, bf16x8 b, f32x4 c) {
    return __builtin_amdgcn_mfma_f32_16x16x32_bf16(a, b, c, 0, 0, 0);
}

// ---------------------------------------------------------------------------
// Convert the six weight matrices f32 -> bf16 into one packed ws region.
// Segment offsets (elements): t_wi 0, t_wo 49152, f_wi 65536, f_wo 114688,
//                             w1 131072, w2 196608, total 262144.
// ---------------------------------------------------------------------------
__global__ __launch_bounds__(256) void cvt_w6(
    const float* __restrict__ s0, const float* __restrict__ s1,
    const float* __restrict__ s2, const float* __restrict__ s3,
    const float* __restrict__ s4, const float* __restrict__ s5,
    bf16* __restrict__ dst)
{
    int i = (blockIdx.x * 256 + threadIdx.x) * 4;
    const float* src; int off;
    if      (i <  49152) { src = s0; off = 0; }
    else if (i <  65536) { src = s1; off = 49152; }
    else if (i < 114688) { src = s2; off = 65536; }
    else if (i < 131072) { src = s3; off = 114688; }
    else if (i < 196608) { src = s4; off = 131072; }
    else                 { src = s5; off = 196608; }
    f32x4 v = *(const f32x4*)&src[i - off];
    bf16x4 b;
    b[0] = (bf16)v[0]; b[1] = (bf16)v[1]; b[2] = (bf16)v[2]; b[3] = (bf16)v[3];
    *(bf16x4*)&dst[i] = b;
}

// ---------------------------------------------------------------------------
// LayerNorm over C=128, one wave per token, 4 tokens per block.
// TRANS=1: write rows reordered [B,T,F] -> [B,F,T] (for temporal attention).
// ---------------------------------------------------------------------------
template<int TRANS>
__global__ __launch_bounds__(256) void ln_k(
    const float* __restrict__ xin, const float* __restrict__ gw,
    const float* __restrict__ gb, bf16* __restrict__ outp)
{
    const int lane = threadIdx.x & 63;
    const int w = threadIdx.x >> 6;
    const int token = blockIdx.x * 4 + w;
    f32x2 v = *(const f32x2*)&xin[(size_t)token * 128 + lane * 2];
    float sm = v[0] + v[1];
    float sq = v[0] * v[0] + v[1] * v[1];
    #pragma unroll
    for (int off = 1; off < 64; off <<= 1) {
        sm += __shfl_xor(sm, off);
        sq += __shfl_xor(sq, off);
    }
    float mu  = sm * 0.0078125f;
    float var = sq * 0.0078125f - mu * mu;
    float rs  = rsqrtf(var + 1e-5f);
    f32x2 gv = *(const f32x2*)&gw[lane * 2];
    f32x2 bv = *(const f32x2*)&gb[lane * 2];
    size_t orow;
    if constexpr (TRANS) {
        int b = token >> 15, t = (token >> 7) & 255, f = token & 127;
        orow = ((size_t)b * 128 + f) * 256 + t;   // [B,F,T] row order
    } else {
        orow = (size_t)token;
    }
    bf16x2 ov;
    ov[0] = (bf16)((v[0] - mu) * rs * gv[0] + bv[0]);
    ov[1] = (bf16)((v[1] - mu) * rs * gv[1] + bv[1]);
    *(bf16x2*)&outp[orow * 128 + lane * 2] = ov;
}

// ---------------------------------------------------------------------------
// GEMM: out[M,N] = epilogue(A[M,K] @ W[N,K]^T + bias[N] (+res[M,N]))
// 128x128 tile, BK=64, 4 waves (2x2 of 64x64), global_load_lds staging.
// ---------------------------------------------------------------------------
template<int OUT_BF16, int RES, int GELU_>
__global__ __launch_bounds__(256) void gemm_bt(
    const bf16* __restrict__ A, const bf16* __restrict__ W,
    const float* __restrict__ bias, const float* __restrict__ res,
    void* __restrict__ outp, int N, int K)
{
    __shared__ __align__(16) bf16 As[128 * 64];
    __shared__ __align__(16) bf16 Bs[128 * 64];
    const int tid  = threadIdx.x;
    const int lane = tid & 63;
    const int wid  = tid >> 6;
    const int m0 = blockIdx.x * 128;
    const int n0 = blockIdx.y * 128;
    const int wm = (wid >> 1) * 64;
    const int wn = (wid & 1) * 64;
    const int g = lane >> 4, li = lane & 15;

    f32x4 acc[4][4] = {};

    for (int k0 = 0; k0 < K; k0 += 64) {
        #pragma unroll
        for (int it = 0; it < 4; ++it) {
            int idx = it * 256 + tid;
            const bf16* gp = A + (size_t)(m0 + (idx >> 3)) * K + k0 + (idx & 7) * 8;
            __builtin_amdgcn_global_load_lds((AS1 void*)gp, (AS3 void*)(As + idx * 8), 16, 0, 0);
        }
        #pragma unroll
        for (int it = 0; it < 4; ++it) {
            int idx = it * 256 + tid;
            const bf16* gp = W + (size_t)(n0 + (idx >> 3)) * K + k0 + (idx & 7) * 8;
            __builtin_amdgcn_global_load_lds((AS1 void*)gp, (AS3 void*)(Bs + idx * 8), 16, 0, 0);
        }
        __syncthreads();
        #pragma unroll
        for (int kk = 0; kk < 2; ++kk) {
            bf16x8 av[4], bv[4];
            #pragma unroll
            for (int i = 0; i < 4; ++i)
                av[i] = *(const bf16x8*)&As[(wm + i * 16 + li) * 64 + kk * 32 + g * 8];
            #pragma unroll
            for (int j = 0; j < 4; ++j)
                bv[j] = *(const bf16x8*)&Bs[(wn + j * 16 + li) * 64 + kk * 32 + g * 8];
            #pragma unroll
            for (int i = 0; i < 4; ++i)
                #pragma unroll
                for (int j = 0; j < 4; ++j)
                    acc[i][j] = mfma16(av[i], bv[j], acc[i][j]);
        }
        __syncthreads();
    }

    #pragma unroll
    for (int j = 0; j < 4; ++j) {
        int col = n0 + wn + j * 16 + li;
        float bv = bias[col];
        #pragma unroll
        for (int i = 0; i < 4; ++i) {
            int row0 = m0 + wm + i * 16 + g * 4;
            #pragma unroll
            for (int r = 0; r < 4; ++r) {
                size_t off = (size_t)(row0 + r) * N + col;
                float v = acc[i][j][r] + bv;
                if constexpr (RES) v += res[off];
                if constexpr (GELU_) v = 0.5f * v * (1.0f + erff(v * 0.70710678118654752f));
                if constexpr (OUT_BF16) ((bf16*)outp)[off] = (bf16)v;
                else ((float*)outp)[off] = v;
            }
        }
    }
}

// ---------------------------------------------------------------------------
// Flash-style attention. MODE 0: causal, S=256, seqs indexed [B,F], output
// rows written back in natural [B,T,F] order. MODE 1: band |i-j|<=16, S=128,
// natural order. 4 heads, dh=32. One wave = 16 query rows; block = 4 waves.
// qkv layout: [seq, pos, 384] bf16 (q | k | v, head-major 32 each).
// ---------------------------------------------------------------------------
template<int MODE>
__global__ __launch_bounds__(256) void attn_k(
    const bf16* __restrict__ qkv, bf16* __restrict__ o)
{
    constexpr int S = (MODE == 0) ? 256 : 128;
    __shared__ __align__(16) bf16 P_lds[4][16][48];
    __shared__ __align__(16) bf16 VT_lds[4][32][48];
    const int lane = threadIdx.x & 63;
    const int w = threadIdx.x >> 6;
    const int g = lane >> 4, li = lane & 15;
    const int s = blockIdx.x;
    const int h = blockIdx.y;
    const int qb = blockIdx.z * 64 + w * 16;

    const size_t base = (size_t)s * S * 384;
    bf16x8 qf = *(const bf16x8*)&qkv[base + (size_t)(qb + li) * 384 + h * 32 + g * 8];

    f32x4 O0 = {0.f, 0.f, 0.f, 0.f}, O1 = {0.f, 0.f, 0.f, 0.f};
    float ms[4], ls[4];
    #pragma unroll
    for (int r = 0; r < 4; ++r) { ms[r] = -1e30f; ls[r] = 0.f; }

    int klo, khi;
    if constexpr (MODE == 0) { klo = 0; khi = qb + 16; }
    else {
        klo = (qb >= 16) ? ((qb - 16) & ~31) : 0;
        khi = (qb + 32 < S) ? (qb + 32) : S;
    }

    const float sc = 0.17677669529663687f;  // 1/sqrt(32)

    for (int k0 = klo; k0 < khi; k0 += 32) {
        bf16x8 kf0 = *(const bf16x8*)&qkv[base + (size_t)(k0 + li) * 384 + 128 + h * 32 + g * 8];
        bf16x8 kf1 = *(const bf16x8*)&qkv[base + (size_t)(k0 + 16 + li) * 384 + 128 + h * 32 + g * 8];
        f32x4 z = {0.f, 0.f, 0.f, 0.f};
        f32x4 s0 = mfma16(qf, kf0, z);
        f32x4 s1 = mfma16(qf, kf1, z);

        // issue V loads early (latency hides under softmax)
        bf16x8 vl0 = *(const bf16x8*)&qkv[base + (size_t)(k0 + (lane >> 2)) * 384 + 256 + h * 32 + (lane & 3) * 8];
        bf16x8 vl1 = *(const bf16x8*)&qkv[base + (size_t)(k0 + 16 + (lane >> 2)) * 384 + 256 + h * 32 + (lane & 3) * 8];

        #pragma unroll
        for (int r = 0; r < 4; ++r) {
            int q = qb + g * 4 + r;
            int c0 = k0 + li, c1 = k0 + 16 + li;
            float v0 = s0[r] * sc, v1 = s1[r] * sc;
            if constexpr (MODE == 0) {
                if (c0 > q) v0 = -1e30f;
                if (c1 > q) v1 = -1e30f;
            } else {
                int d0 = c0 - q, d1 = c1 - q;
                if (d0 > 16 || d0 < -16) v0 = -1e30f;
                if (d1 > 16 || d1 < -16) v1 = -1e30f;
            }
            float mx = fmaxf(v0, v1);
            #pragma unroll
            for (int off = 1; off < 16; off <<= 1) mx = fmaxf(mx, __shfl_xor(mx, off));
            float mn = fmaxf(ms[r], mx);
            float scale = __expf(ms[r] - mn);
            ms[r] = mn;
            float p0 = __expf(v0 - mn), p1 = __expf(v1 - mn);
            float ps = p0 + p1;
            #pragma unroll
            for (int off = 1; off < 16; off <<= 1) ps += __shfl_xor(ps, off);
            ls[r] = ls[r] * scale + ps;
            O0[r] *= scale; O1[r] *= scale;
            P_lds[w][g * 4 + r][li]      = (bf16)p0;
            P_lds[w][g * 4 + r][16 + li] = (bf16)p1;
        }

        // stage V transposed: VT[d][k]
        #pragma unroll
        for (int e = 0; e < 8; ++e) {
            VT_lds[w][(lane & 3) * 8 + e][lane >> 2]        = vl0[e];
            VT_lds[w][(lane & 3) * 8 + e][16 + (lane >> 2)] = vl1[e];
        }

        bf16x8 pa  = *(const bf16x8*)&P_lds[w][li][g * 8];
        bf16x8 vb0 = *(const bf16x8*)&VT_lds[w][li][g * 8];
        bf16x8 vb1 = *(const bf16x8*)&VT_lds[w][16 + li][g * 8];
        O0 = mfma16(pa, vb0, O0);
        O1 = mfma16(pa, vb1, O1);
    }

    #pragma unroll
    for (int r = 0; r < 4; ++r) {
        float inv = 1.0f / ls[r];
        int q = qb + g * 4 + r;
        size_t orow;
        if constexpr (MODE == 0) {
            int b = s >> 7, f = s & 127;
            orow = ((size_t)(b * 256 + q)) * 128 + f;   // back to [B,T,F]
        } else {
            orow = (size_t)s * 128 + q;
        }
        o[orow * 128 + h * 32 + li]      = (bf16)(O0[r] * inv);
        o[orow * 128 + h * 32 + 16 + li] = (bf16)(O1[r] * inv);
    }
}

// ---------------------------------------------------------------------------
extern "C" void kernel_launch(void* const* d_in, const int* in_sizes, int n_in,
                              void* d_out, int out_size, void* d_ws, size_t ws_size,
                              hipStream_t stream) {
    const float* x      = (const float*)d_in[0];
    const float* ln_t_w = (const float*)d_in[1];
    const float* ln_t_b = (const float*)d_in[2];
    const float* t_wi   = (const float*)d_in[3];
    const float* t_bi   = (const float*)d_in[4];
    const float* t_wo   = (const float*)d_in[5];
    const float* t_bo   = (const float*)d_in[6];
    const float* ln_f_w = (const float*)d_in[7];
    const float* ln_f_b = (const float*)d_in[8];
    const float* f_wi   = (const float*)d_in[9];
    const float* f_bi   = (const float*)d_in[10];
    const float* f_wo   = (const float*)d_in[11];
    const float* f_bo   = (const float*)d_in[12];
    const float* ln_n_w = (const float*)d_in[13];
    const float* ln_n_b = (const float*)d_in[14];
    const float* w1     = (const float*)d_in[15];
    const float* b1     = (const float*)d_in[16];
    const float* w2     = (const float*)d_in[17];
    const float* b2     = (const float*)d_in[18];

    char* ws = (char*)d_ws;
    bf16* wbf  = (bf16*)ws;                                      // 512 KB
    bf16* xn   = (bf16*)(ws + 524288);                           // 16 MB
    bf16* qkvh = (bf16*)(ws + 524288 + 16777216);                // 64 MB (qkv / h)
    bf16* obf  = (bf16*)(ws + 524288 + 16777216 + 67108864);     // 16 MB
    float* xcur = (float*)(ws + 524288 + 16777216 + 67108864 + 16777216); // 32 MB
    float* out = (float*)d_out;

    const bf16* twi_b = wbf + 0;
    const bf16* two_b = wbf + 49152;
    const bf16* fwi_b = wbf + 65536;
    const bf16* fwo_b = wbf + 114688;
    const bf16* w1_b  = wbf + 131072;
    const bf16* w2_b  = wbf + 196608;

    // 0) weights -> bf16
    cvt_w6<<<256, 256, 0, stream>>>(t_wi, t_wo, f_wi, f_wo, w1, w2, wbf);

    // 1) temporal: LN (transposed write), QKV, attention (causal), out-proj + residual
    ln_k<1><<<16384, 256, 0, stream>>>(x, ln_t_w, ln_t_b, xn);
    gemm_bt<1, 0, 0><<<dim3(512, 3), 256, 0, stream>>>(xn, twi_b, t_bi, nullptr, qkvh, 384, 128);
    attn_k<0><<<dim3(256, 4, 4), 256, 0, stream>>>(qkvh, obf);
    gemm_bt<0, 1, 0><<<dim3(512, 1), 256, 0, stream>>>(obf, two_b, t_bo, x, xcur, 128, 128);

    // 2) frequency: LN, QKV, attention (band), out-proj + residual (in-place)
    ln_k<0><<<16384, 256, 0, stream>>>(xcur, ln_f_w, ln_f_b, xn);
    gemm_bt<1, 0, 0><<<dim3(512, 3), 256, 0, stream>>>(xn, fwi_b, f_bi, nullptr, qkvh, 384, 128);
    attn_k<1><<<dim3(512, 4, 2), 256, 0, stream>>>(qkvh, obf);
    gemm_bt<0, 1, 0><<<dim3(512, 1), 256, 0, stream>>>(obf, fwo_b, f_bo, xcur, xcur, 128, 128);

    // 3) FFN: LN, W1+GELU, W2 + residual -> d_out
    ln_k<0><<<16384, 256, 0, stream>>>(xcur, ln_n_w, ln_n_b, xn);
    gemm_bt<1, 0, 1><<<dim3(512, 4), 256, 0, stream>>>(xn, w1_b, b1, nullptr, qkvh, 512, 128);
    gemm_bt<0, 1, 0><<<dim3(512, 1), 256, 0, stream>>>(qkvh, w2_b, b2, xcur, out, 128, 512);

    (void)in_sizes; (void)n_in; (void)out_size; (void)ws_size;
}

// Round 2
// 227.313 us; speedup vs baseline: 1.1186x; 1.1186x over previous
//
#include <hip/hip_runtime.h>
#include <math.h>

typedef __bf16 bf16;
typedef __bf16 bf16x8 __attribute__((ext_vector_type(8)));
typedef __bf16 bf16x4 __attribute__((ext_vector_type(4)));
typedef __bf16 bf16x2 __attribute__((ext_vector_type(2)));
typedef float f32x4 __attribute__((ext_vector_type(4)));
typedef float f32x2 __attribute__((ext_vector_type(2)));
typedef float f32x16 __attribute__((ext_vector_type(16)));
typedef unsigned int u32;
typedef unsigned int u32x4 __attribute__((ext_vector_type(4)));

#define AS1 __attribute__((address_space(1)))
#define AS3 __attribute__((address_space(3)))

static __device__ __forceinline__ f32x4 mfma16(bf16x8 a, bf16x8 b, f32x4 c) {
    return __builtin_amdgcn_mfma_f32_16x16x32_bf16(a, b, c, 0, 0, 0);
}
static __device__ __forceinline__ f32x16 mfma32(bf16x8 a, bf16x8 b, f32x16 c) {
    return __builtin_amdgcn_mfma_f32_32x32x16_bf16(a, b, c, 0, 0, 0);
}
static __device__ __forceinline__ u32 pk2(float a, float b) {
    bf16x2 v; v[0] = (bf16)a; v[1] = (bf16)b;
    return __builtin_bit_cast(u32, v);
}

// ---------------------------------------------------------------------------
// Convert the six weight matrices f32 -> bf16 into one packed ws region.
// ---------------------------------------------------------------------------
__global__ __launch_bounds__(256) void cvt_w6(
    const float* __restrict__ s0, const float* __restrict__ s1,
    const float* __restrict__ s2, const float* __restrict__ s3,
    const float* __restrict__ s4, const float* __restrict__ s5,
    bf16* __restrict__ dst)
{
    int i = (blockIdx.x * 256 + threadIdx.x) * 4;
    const float* src; int off;
    if      (i <  49152) { src = s0; off = 0; }
    else if (i <  65536) { src = s1; off = 49152; }
    else if (i < 114688) { src = s2; off = 65536; }
    else if (i < 131072) { src = s3; off = 114688; }
    else if (i < 196608) { src = s4; off = 131072; }
    else                 { src = s5; off = 196608; }
    f32x4 v = *(const f32x4*)&src[i - off];
    bf16x4 b;
    b[0] = (bf16)v[0]; b[1] = (bf16)v[1]; b[2] = (bf16)v[2]; b[3] = (bf16)v[3];
    *(bf16x4*)&dst[i] = b;
}

// ---------------------------------------------------------------------------
// LayerNorm over C=128, one wave per token, 4 tokens per block.
// TRANS=1: write rows reordered [B,T,F] -> [B,F,T] (for temporal attention).
// ---------------------------------------------------------------------------
template<int TRANS>
__global__ __launch_bounds__(256) void ln_k(
    const float* __restrict__ xin, const float* __restrict__ gw,
    const float* __restrict__ gb, bf16* __restrict__ outp)
{
    const int lane = threadIdx.x & 63;
    const int w = threadIdx.x >> 6;
    const int token = blockIdx.x * 4 + w;
    f32x2 v = *(const f32x2*)&xin[(size_t)token * 128 + lane * 2];
    float sm = v[0] + v[1];
    float sq = v[0] * v[0] + v[1] * v[1];
    #pragma unroll
    for (int off = 1; off < 64; off <<= 1) {
        sm += __shfl_xor(sm, off);
        sq += __shfl_xor(sq, off);
    }
    float mu  = sm * 0.0078125f;
    float var = sq * 0.0078125f - mu * mu;
    float rs  = rsqrtf(var + 1e-5f);
    f32x2 gv = *(const f32x2*)&gw[lane * 2];
    f32x2 bv = *(const f32x2*)&gb[lane * 2];
    size_t orow;
    if constexpr (TRANS) {
        int b = token >> 15, t = (token >> 7) & 255, f = token & 127;
        orow = ((size_t)b * 128 + f) * 256 + t;   // [B,F,T] row order
    } else {
        orow = (size_t)token;
    }
    bf16x2 ov;
    ov[0] = (bf16)((v[0] - mu) * rs * gv[0] + bv[0]);
    ov[1] = (bf16)((v[1] - mu) * rs * gv[1] + bv[1]);
    *(bf16x2*)&outp[orow * 128 + lane * 2] = ov;
}

// ---------------------------------------------------------------------------
// GEMM: out[M,N] = epilogue(A[M,K] @ W[N,K]^T + bias[N] (+res[M,N]))
// 128x128 tile, BK=64, 4 waves (2x2 of 64x64), global_load_lds staging.
// ---------------------------------------------------------------------------
template<int OUT_BF16, int RES, int GELU_>
__global__ __launch_bounds__(256) void gemm_bt(
    const bf16* __restrict__ A, const bf16* __restrict__ W,
    const float* __restrict__ bias, const float* __restrict__ res,
    void* __restrict__ outp, int N, int K)
{
    __shared__ __align__(16) bf16 As[128 * 64];
    __shared__ __align__(16) bf16 Bs[128 * 64];
    const int tid  = threadIdx.x;
    const int lane = tid & 63;
    const int wid  = tid >> 6;
    const int m0 = blockIdx.x * 128;
    const int n0 = blockIdx.y * 128;
    const int wm = (wid >> 1) * 64;
    const int wn = (wid & 1) * 64;
    const int g = lane >> 4, li = lane & 15;

    f32x4 acc[4][4] = {};

    for (int k0 = 0; k0 < K; k0 += 64) {
        #pragma unroll
        for (int it = 0; it < 4; ++it) {
            int idx = it * 256 + tid;
            const bf16* gp = A + (size_t)(m0 + (idx >> 3)) * K + k0 + (idx & 7) * 8;
            __builtin_amdgcn_global_load_lds((AS1 void*)gp, (AS3 void*)(As + idx * 8), 16, 0, 0);
        }
        #pragma unroll
        for (int it = 0; it < 4; ++it) {
            int idx = it * 256 + tid;
            const bf16* gp = W + (size_t)(n0 + (idx >> 3)) * K + k0 + (idx & 7) * 8;
            __builtin_amdgcn_global_load_lds((AS1 void*)gp, (AS3 void*)(Bs + idx * 8), 16, 0, 0);
        }
        __syncthreads();
        #pragma unroll
        for (int kk = 0; kk < 2; ++kk) {
            bf16x8 av[4], bv[4];
            #pragma unroll
            for (int i = 0; i < 4; ++i)
                av[i] = *(const bf16x8*)&As[(wm + i * 16 + li) * 64 + kk * 32 + g * 8];
            #pragma unroll
            for (int j = 0; j < 4; ++j)
                bv[j] = *(const bf16x8*)&Bs[(wn + j * 16 + li) * 64 + kk * 32 + g * 8];
            #pragma unroll
            for (int i = 0; i < 4; ++i)
                #pragma unroll
                for (int j = 0; j < 4; ++j)
                    acc[i][j] = mfma16(av[i], bv[j], acc[i][j]);
        }
        __syncthreads();
    }

    #pragma unroll
    for (int j = 0; j < 4; ++j) {
        int col = n0 + wn + j * 16 + li;
        float bv = bias[col];
        #pragma unroll
        for (int i = 0; i < 4; ++i) {
            int row0 = m0 + wm + i * 16 + g * 4;
            #pragma unroll
            for (int r = 0; r < 4; ++r) {
                size_t off = (size_t)(row0 + r) * N + col;
                float v = acc[i][j][r] + bv;
                if constexpr (RES) v += res[off];
                if constexpr (GELU_) v = 0.5f * v * (1.0f + erff(v * 0.70710678118654752f));
                if constexpr (OUT_BF16) ((bf16*)outp)[off] = (bf16)v;
                else ((float*)outp)[off] = v;
            }
        }
    }
}

// ---------------------------------------------------------------------------
// Flash attention, swapped-operand in-register form (no LDS).
// One wave = 32 q rows x full dh=32, one (seq, head) per wave group.
// S^T = mfma32(K_frag, Q_frag): lane owns q = lane&31; 16 k-scores in regs,
// lane^32 holds the other 16. Softmax per-lane scalar (m, l lane-uniform).
// P packed to bf16 + 8 shfl_xor(32) -> B-frag; O^T = mfma32(V^T_frag, P_frag).
// MODE 0: causal, S=256, seqs [B,F], out rows in [B,T,F] order.
// MODE 1: band |i-j|<=16, S=128, natural order.
// ---------------------------------------------------------------------------
template<int MODE>
__global__ __launch_bounds__(256) void attn_k(
    const bf16* __restrict__ qkv, bf16* __restrict__ o)
{
    constexpr int S = (MODE == 0) ? 256 : 128;
    const int lane = threadIdx.x & 63;
    const int w = threadIdx.x >> 6;
    const int hi = lane >> 5;
    const int q31 = lane & 31;
    const int s = blockIdx.x;
    const int h = blockIdx.y;
    const int qb = (MODE == 0) ? ((int)blockIdx.z * 128 + w * 32) : (w * 32);
    const int q = qb + q31;

    const size_t base = (size_t)s * S * 384;
    const bf16* qp = qkv + base + h * 32;
    const bf16* kp = qp + 128;
    const bf16* vp = qp + 256 + q31;   // column d = lane&31 of V

    // Q as B-operand: lane holds Q[q][hi*8+e] (c 0..15) / Q[q][16+hi*8+e]
    bf16x8 qf0 = *(const bf16x8*)&qp[(size_t)q * 384 + hi * 8];
    bf16x8 qf1 = *(const bf16x8*)&qp[(size_t)q * 384 + 16 + hi * 8];

    f32x16 O = {};
    float m = -1e30f, l = 0.f;

    int klo, khi;
    if constexpr (MODE == 0) { klo = 0; khi = qb + 32; }
    else {
        klo = (qb > 16 ? (qb - 16) : 0) & ~31;
        khi = (qb + 48 < S) ? (qb + 48) : S;
    }

    const float sc = 0.17677669529663687f;  // 1/sqrt(32)

    for (int k0 = klo; k0 < khi; k0 += 32) {
        // K as A-operand: lane holds K[k0+q31][hi*8+e] / [16+hi*8+e]
        bf16x8 kf0 = *(const bf16x8*)&kp[(size_t)(k0 + q31) * 384 + hi * 8];
        bf16x8 kf1 = *(const bf16x8*)&kp[(size_t)(k0 + q31) * 384 + 16 + hi * 8];
        // V^T as A-operand for PV (issue early; strided scalar, L1/L2-hit)
        bf16x8 vf1, vf2;
        #pragma unroll
        for (int e = 0; e < 8; ++e) {
            vf1[e] = vp[(size_t)(k0 + hi * 8 + e) * 384];
            vf2[e] = vp[(size_t)(k0 + 16 + hi * 8 + e) * 384];
        }

        f32x16 st = {};
        st = mfma32(kf0, qf0, st);
        st = mfma32(kf1, qf1, st);

        float mx = -3.0e38f;
        #pragma unroll
        for (int r = 0; r < 16; ++r) {
            int krow = k0 + (r & 3) + 8 * (r >> 2) + 4 * hi;
            bool ok;
            if constexpr (MODE == 0) ok = (krow <= q);
            else { int d = krow - q; ok = (d <= 16 && d >= -16); }
            float v = ok ? st[r] * sc : -3.0e38f;
            st[r] = v;
            mx = fmaxf(mx, v);
        }
        mx = fmaxf(mx, __shfl_xor(mx, 32));
        float mn = fmaxf(m, mx);
        float resc = __expf(m - mn);
        m = mn;
        float ps = 0.f;
        #pragma unroll
        for (int r = 0; r < 16; ++r) {
            float p = __expf(st[r] - mn);
            st[r] = p;
            ps += p;
        }
        ps += __shfl_xor(ps, 32);
        l = l * resc + ps;
        #pragma unroll
        for (int r = 0; r < 16; ++r) O[r] *= resc;

        // P -> bf16 B-frag (k = hi*8+e layout) via pack + half-swap
        u32 c01 = pk2(st[0], st[1]),   c23 = pk2(st[2], st[3]);
        u32 c45 = pk2(st[4], st[5]),   c67 = pk2(st[6], st[7]);
        u32 c89 = pk2(st[8], st[9]),   cAB = pk2(st[10], st[11]);
        u32 cCD = pk2(st[12], st[13]), cEF = pk2(st[14], st[15]);
        u32 x01 = __shfl_xor((int)c01, 32), x23 = __shfl_xor((int)c23, 32);
        u32 x45 = __shfl_xor((int)c45, 32), x67 = __shfl_xor((int)c67, 32);
        u32 x89 = __shfl_xor((int)c89, 32), xAB = __shfl_xor((int)cAB, 32);
        u32 xCD = __shfl_xor((int)cCD, 32), xEF = __shfl_xor((int)cEF, 32);
        u32x4 b1w = hi ? u32x4{x45, x67, c45, c67} : u32x4{c01, c23, x01, x23};
        u32x4 b2w = hi ? u32x4{xCD, xEF, cCD, cEF} : u32x4{c89, cAB, x89, xAB};
        bf16x8 B1 = __builtin_bit_cast(bf16x8, b1w);
        bf16x8 B2 = __builtin_bit_cast(bf16x8, b2w);

        O = mfma32(vf1, B1, O);
        O = mfma32(vf2, B2, O);
    }

    float inv = 1.f / l;
    size_t orow;
    if constexpr (MODE == 0) {
        int b = s >> 7, f = s & 127;
        orow = ((size_t)(b * 256 + q)) * 128 + f;   // back to [B,T,F]
    } else {
        orow = (size_t)s * 128 + q;
    }
    bf16* op = o + orow * 128 + h * 32;
    #pragma unroll
    for (int mb = 0; mb < 4; ++mb) {
        bf16x4 ov;
        #pragma unroll
        for (int j = 0; j < 4; ++j) ov[j] = (bf16)(O[mb * 4 + j] * inv);
        *(bf16x4*)&op[mb * 8 + hi * 4] = ov;   // d = mb*8 + hi*4 + j
    }
}

// ---------------------------------------------------------------------------
extern "C" void kernel_launch(void* const* d_in, const int* in_sizes, int n_in,
                              void* d_out, int out_size, void* d_ws, size_t ws_size,
                              hipStream_t stream) {
    const float* x      = (const float*)d_in[0];
    const float* ln_t_w = (const float*)d_in[1];
    const float* ln_t_b = (const float*)d_in[2];
    const float* t_wi   = (const float*)d_in[3];
    const float* t_bi   = (const float*)d_in[4];
    const float* t_wo   = (const float*)d_in[5];
    const float* t_bo   = (const float*)d_in[6];
    const float* ln_f_w = (const float*)d_in[7];
    const float* ln_f_b = (const float*)d_in[8];
    const float* f_wi   = (const float*)d_in[9];
    const float* f_bi   = (const float*)d_in[10];
    const float* f_wo   = (const float*)d_in[11];
    const float* f_bo   = (const float*)d_in[12];
    const float* ln_n_w = (const float*)d_in[13];
    const float* ln_n_b = (const float*)d_in[14];
    const float* w1     = (const float*)d_in[15];
    const float* b1     = (const float*)d_in[16];
    const float* w2     = (const float*)d_in[17];
    const float* b2     = (const float*)d_in[18];

    char* ws = (char*)d_ws;
    bf16* wbf  = (bf16*)ws;                                      // 512 KB
    bf16* xn   = (bf16*)(ws + 524288);                           // 16 MB
    bf16* qkvh = (bf16*)(ws + 524288 + 16777216);                // 64 MB (qkv / h)
    bf16* obf  = (bf16*)(ws + 524288 + 16777216 + 67108864);     // 16 MB
    float* xcur = (float*)(ws + 524288 + 16777216 + 67108864 + 16777216); // 32 MB
    float* out = (float*)d_out;

    const bf16* twi_b = wbf + 0;
    const bf16* two_b = wbf + 49152;
    const bf16* fwi_b = wbf + 65536;
    const bf16* fwo_b = wbf + 114688;
    const bf16* w1_b  = wbf + 131072;
    const bf16* w2_b  = wbf + 196608;

    // 0) weights -> bf16
    cvt_w6<<<256, 256, 0, stream>>>(t_wi, t_wo, f_wi, f_wo, w1, w2, wbf);

    // 1) temporal: LN (transposed write), QKV, attention (causal), out-proj + residual
    ln_k<1><<<16384, 256, 0, stream>>>(x, ln_t_w, ln_t_b, xn);
    gemm_bt<1, 0, 0><<<dim3(512, 3), 256, 0, stream>>>(xn, twi_b, t_bi, nullptr, qkvh, 384, 128);
    attn_k<0><<<dim3(256, 4, 2), 256, 0, stream>>>(qkvh, obf);
    gemm_bt<0, 1, 0><<<dim3(512, 1), 256, 0, stream>>>(obf, two_b, t_bo, x, xcur, 128, 128);

    // 2) frequency: LN, QKV, attention (band), out-proj + residual (in-place)
    ln_k<0><<<16384, 256, 0, stream>>>(xcur, ln_f_w, ln_f_b, xn);
    gemm_bt<1, 0, 0><<<dim3(512, 3), 256, 0, stream>>>(xn, fwi_b, f_bi, nullptr, qkvh, 384, 128);
    attn_k<1><<<dim3(512, 4), 256, 0, stream>>>(qkvh, obf);
    gemm_bt<0, 1, 0><<<dim3(512, 1), 256, 0, stream>>>(obf, fwo_b, f_bo, xcur, xcur, 128, 128);

    // 3) FFN: LN, W1+GELU, W2 + residual -> d_out
    ln_k<0><<<16384, 256, 0, stream>>>(xcur, ln_n_w, ln_n_b, xn);
    gemm_bt<1, 0, 1><<<dim3(512, 4), 256, 0, stream>>>(xn, w1_b, b1, nullptr, qkvh, 512, 128);
    gemm_bt<0, 1, 0><<<dim3(512, 1), 256, 0, stream>>>(qkvh, w2_b, b2, xcur, out, 128, 512);

    (void)in_sizes; (void)n_in; (void)out_size; (void)ws_size;
}

// Round 3
// 200.171 us; speedup vs baseline: 1.2702x; 1.1356x over previous
//
#include <hip/hip_runtime.h>
#include <math.h>

typedef __bf16 bf16;
typedef __bf16 bf16x8 __attribute__((ext_vector_type(8)));
typedef __bf16 bf16x4 __attribute__((ext_vector_type(4)));
typedef __bf16 bf16x2 __attribute__((ext_vector_type(2)));
typedef float f32x4 __attribute__((ext_vector_type(4)));
typedef float f32x2 __attribute__((ext_vector_type(2)));
typedef float f32x16 __attribute__((ext_vector_type(16)));
typedef unsigned int u32;
typedef unsigned int u32x4 __attribute__((ext_vector_type(4)));

#define AS1 __attribute__((address_space(1)))
#define AS3 __attribute__((address_space(3)))

static __device__ __forceinline__ f32x4 mfma16(bf16x8 a, bf16x8 b, f32x4 c) {
    return __builtin_amdgcn_mfma_f32_16x16x32_bf16(a, b, c, 0, 0, 0);
}
static __device__ __forceinline__ f32x16 mfma32(bf16x8 a, bf16x8 b, f32x16 c) {
    return __builtin_amdgcn_mfma_f32_32x32x16_bf16(a, b, c, 0, 0, 0);
}
static __device__ __forceinline__ u32 pk2(float a, float b) {
    bf16x2 v; v[0] = (bf16)a; v[1] = (bf16)b;
    return __builtin_bit_cast(u32, v);
}
// exact-enough GELU: Abramowitz-Stegun 7.1.26 erf (max abs err 1.5e-7)
static __device__ __forceinline__ float gelu_f(float x) {
    float ax = fabsf(x);
    float t = 1.0f / (1.0f + 0.3275911f * ax);
    float y = t * (0.254829592f + t * (-0.284496736f + t * (1.421413741f +
              t * (-1.453152027f + t * 1.061405429f))));
    float er = 1.0f - y * __expf(-ax * ax);
    er = copysignf(er, x);
    return 0.5f * x * (1.0f + er);
}

// ---------------------------------------------------------------------------
// Convert the six weight matrices f32 -> bf16 into one packed ws region.
// ---------------------------------------------------------------------------
__global__ __launch_bounds__(256) void cvt_w6(
    const float* __restrict__ s0, const float* __restrict__ s1,
    const float* __restrict__ s2, const float* __restrict__ s3,
    const float* __restrict__ s4, const float* __restrict__ s5,
    bf16* __restrict__ dst)
{
    int i = (blockIdx.x * 256 + threadIdx.x) * 4;
    const float* src; int off;
    if      (i <  49152) { src = s0; off = 0; }
    else if (i <  65536) { src = s1; off = 49152; }
    else if (i < 114688) { src = s2; off = 65536; }
    else if (i < 131072) { src = s3; off = 114688; }
    else if (i < 196608) { src = s4; off = 131072; }
    else                 { src = s5; off = 196608; }
    f32x4 v = *(const f32x4*)&src[i - off];
    bf16x4 b;
    b[0] = (bf16)v[0]; b[1] = (bf16)v[1]; b[2] = (bf16)v[2]; b[3] = (bf16)v[3];
    *(bf16x4*)&dst[i] = b;
}

// ---------------------------------------------------------------------------
// LayerNorm over C=128 (standalone, only for the first stage), one wave/token.
// Writes rows reordered [B,T,F] -> [B,F,T] for the temporal attention.
// ---------------------------------------------------------------------------
__global__ __launch_bounds__(256) void ln_t_k(
    const float* __restrict__ xin, const float* __restrict__ gw,
    const float* __restrict__ gb, bf16* __restrict__ outp)
{
    const int lane = threadIdx.x & 63;
    const int w = threadIdx.x >> 6;
    const int token = blockIdx.x * 4 + w;
    f32x2 v = *(const f32x2*)&xin[(size_t)token * 128 + lane * 2];
    float sm = v[0] + v[1];
    float sq = v[0] * v[0] + v[1] * v[1];
    #pragma unroll
    for (int off = 1; off < 64; off <<= 1) {
        sm += __shfl_xor(sm, off);
        sq += __shfl_xor(sq, off);
    }
    float mu  = sm * 0.0078125f;
    float var = sq * 0.0078125f - mu * mu;
    float rs  = rsqrtf(var + 1e-5f);
    f32x2 gv = *(const f32x2*)&gw[lane * 2];
    f32x2 bv = *(const f32x2*)&gb[lane * 2];
    int b = token >> 15, t = (token >> 7) & 255, f = token & 127;
    size_t orow = ((size_t)b * 128 + f) * 256 + t;   // [B,F,T] row order
    bf16x2 ov;
    ov[0] = (bf16)((v[0] - mu) * rs * gv[0] + bv[0]);
    ov[1] = (bf16)((v[1] - mu) * rs * gv[1] + bv[1]);
    *(bf16x2*)&outp[orow * 128 + lane * 2] = ov;
}

// ---------------------------------------------------------------------------
// Row-wave GEMM: out[M,N] = epi(A[M,K] @ W[N,K]^T + bias (+res))
// Block = 64 rows x 128 cols, 4 waves; each wave owns 16 FULL rows.
// A-frags straight from global to regs (no LDS); W staged via global_load_lds
// with XOR bank swizzle (pre-swizzled source + swizzled ds_read).
// LNF=1 (requires N==128): fused LayerNorm epilogue -> xnout (bf16), main out
// gets the pre-LN value (residual stream).
// ---------------------------------------------------------------------------
template<int OUT_BF16, int RES, int GELU_, int LNF>
__global__ __launch_bounds__(256) void gemm_rw(
    const bf16* __restrict__ A, const bf16* __restrict__ W,
    const float* __restrict__ bias, const float* __restrict__ res,
    void* __restrict__ outp, bf16* __restrict__ xnout,
    const float* __restrict__ lnw, const float* __restrict__ lnb,
    int N, int K)
{
    __shared__ __align__(16) bf16 Bs[128 * 64];
    const int tid  = threadIdx.x;
    const int lane = tid & 63;
    const int w    = tid >> 6;
    const int li = lane & 15, g = lane >> 4;
    const int m0 = blockIdx.x * 64;
    const int n0 = blockIdx.y * 128;
    const int arow = m0 + w * 16 + li;
    const bf16* ap = A + (size_t)arow * K;

    f32x4 acc[8] = {};

    for (int k0 = 0; k0 < K; k0 += 64) {
        #pragma unroll
        for (int it = 0; it < 4; ++it) {
            int idx = it * 256 + tid;
            int brow = idx >> 3, bch = idx & 7;
            const bf16* gp = W + (size_t)(n0 + brow) * K + k0 + ((bch ^ (brow & 7)) * 8);
            __builtin_amdgcn_global_load_lds((AS1 void*)gp, (AS3 void*)(Bs + idx * 8), 16, 0, 0);
        }
        bf16x8 av0 = *(const bf16x8*)&ap[k0 + g * 8];
        bf16x8 av1 = *(const bf16x8*)&ap[k0 + 32 + g * 8];
        __syncthreads();
        #pragma unroll
        for (int kk = 0; kk < 2; ++kk) {
            bf16x8 av = kk ? av1 : av0;
            #pragma unroll
            for (int j = 0; j < 8; ++j) {
                int brow = j * 16 + li;
                int bch = (kk * 4 + g) ^ (li & 7);
                bf16x8 bv = *(const bf16x8*)&Bs[brow * 64 + bch * 8];
                acc[j] = mfma16(av, bv, acc[j]);
            }
        }
        __syncthreads();
    }

    float bcol[8], lw[8], lb[8];
    #pragma unroll
    for (int j = 0; j < 8; ++j) {
        bcol[j] = bias[n0 + j * 16 + li];
        if constexpr (LNF) { lw[j] = lnw[j * 16 + li]; lb[j] = lnb[j * 16 + li]; }
    }

    const int row0 = m0 + w * 16 + g * 4;
    #pragma unroll
    for (int r = 0; r < 4; ++r) {
        int row = row0 + r;
        float vals[8];
        #pragma unroll
        for (int j = 0; j < 8; ++j) {
            float v = acc[j][r] + bcol[j];
            if constexpr (RES) v += res[(size_t)row * N + n0 + j * 16 + li];
            if constexpr (GELU_) v = gelu_f(v);
            vals[j] = v;
        }
        #pragma unroll
        for (int j = 0; j < 8; ++j) {
            size_t off = (size_t)row * N + n0 + j * 16 + li;
            if constexpr (OUT_BF16) ((bf16*)outp)[off] = (bf16)vals[j];
            else                    ((float*)outp)[off] = vals[j];
        }
        if constexpr (LNF) {
            float sm = 0.f, sq = 0.f;
            #pragma unroll
            for (int j = 0; j < 8; ++j) { sm += vals[j]; sq += vals[j] * vals[j]; }
            #pragma unroll
            for (int off = 1; off < 16; off <<= 1) {
                sm += __shfl_xor(sm, off);
                sq += __shfl_xor(sq, off);
            }
            float mu  = sm * 0.0078125f;
            float var = sq * 0.0078125f - mu * mu;
            float rs  = rsqrtf(var + 1e-5f);
            #pragma unroll
            for (int j = 0; j < 8; ++j)
                xnout[(size_t)row * 128 + j * 16 + li] =
                    (bf16)((vals[j] - mu) * rs * lw[j] + lb[j]);
        }
    }
}

// ---------------------------------------------------------------------------
// Flash attention, swapped-operand in-register form (no LDS).
// MODE 0: causal S=256, seqs [B,F], out rows in [B,T,F]. MODE 1: band +-16,
// S=128. One wave = 32 q rows x dh=32; lane owns q = lane&31.
// ---------------------------------------------------------------------------
template<int MODE>
__global__ __launch_bounds__(256) void attn_k(
    const bf16* __restrict__ qkv, bf16* __restrict__ o)
{
    constexpr int S = (MODE == 0) ? 256 : 128;
    const int lane = threadIdx.x & 63;
    const int w = threadIdx.x >> 6;
    const int hi = lane >> 5;
    const int q31 = lane & 31;
    const int s = blockIdx.x;
    const int h = blockIdx.y;
    const int qb = (MODE == 0) ? ((int)blockIdx.z * 128 + w * 32) : (w * 32);
    const int q = qb + q31;

    const size_t base = (size_t)s * S * 384;
    const bf16* qp = qkv + base + h * 32;
    const bf16* kp = qp + 128;
    const bf16* vp = qp + 256 + q31;

    bf16x8 qf0 = *(const bf16x8*)&qp[(size_t)q * 384 + hi * 8];
    bf16x8 qf1 = *(const bf16x8*)&qp[(size_t)q * 384 + 16 + hi * 8];

    f32x16 O = {};
    float m = -1e30f, l = 0.f;

    int klo, khi;
    if constexpr (MODE == 0) { klo = 0; khi = qb + 32; }
    else {
        klo = (qb > 16 ? (qb - 16) : 0) & ~31;
        khi = (qb + 48 < S) ? (qb + 48) : S;
    }

    const float sc = 0.17677669529663687f;  // 1/sqrt(32)

    for (int k0 = klo; k0 < khi; k0 += 32) {
        bf16x8 kf0 = *(const bf16x8*)&kp[(size_t)(k0 + q31) * 384 + hi * 8];
        bf16x8 kf1 = *(const bf16x8*)&kp[(size_t)(k0 + q31) * 384 + 16 + hi * 8];
        bf16x8 vf1, vf2;
        #pragma unroll
        for (int e = 0; e < 8; ++e) {
            vf1[e] = vp[(size_t)(k0 + hi * 8 + e) * 384];
            vf2[e] = vp[(size_t)(k0 + 16 + hi * 8 + e) * 384];
        }

        f32x16 st = {};
        st = mfma32(kf0, qf0, st);
        st = mfma32(kf1, qf1, st);

        float mx = -3.0e38f;
        #pragma unroll
        for (int r = 0; r < 16; ++r) {
            int krow = k0 + (r & 3) + 8 * (r >> 2) + 4 * hi;
            bool ok;
            if constexpr (MODE == 0) ok = (krow <= q);
            else { int d = krow - q; ok = (d <= 16 && d >= -16); }
            float v = ok ? st[r] * sc : -3.0e38f;
            st[r] = v;
            mx = fmaxf(mx, v);
        }
        mx = fmaxf(mx, __shfl_xor(mx, 32));
        float mn = fmaxf(m, mx);
        float resc = __expf(m - mn);
        m = mn;
        float ps = 0.f;
        #pragma unroll
        for (int r = 0; r < 16; ++r) {
            float p = __expf(st[r] - mn);
            st[r] = p;
            ps += p;
        }
        ps += __shfl_xor(ps, 32);
        l = l * resc + ps;
        #pragma unroll
        for (int r = 0; r < 16; ++r) O[r] *= resc;

        u32 c01 = pk2(st[0], st[1]),   c23 = pk2(st[2], st[3]);
        u32 c45 = pk2(st[4], st[5]),   c67 = pk2(st[6], st[7]);
        u32 c89 = pk2(st[8], st[9]),   cAB = pk2(st[10], st[11]);
        u32 cCD = pk2(st[12], st[13]), cEF = pk2(st[14], st[15]);
        u32 x01 = __shfl_xor((int)c01, 32), x23 = __shfl_xor((int)c23, 32);
        u32 x45 = __shfl_xor((int)c45, 32), x67 = __shfl_xor((int)c67, 32);
        u32 x89 = __shfl_xor((int)c89, 32), xAB = __shfl_xor((int)cAB, 32);
        u32 xCD = __shfl_xor((int)cCD, 32), xEF = __shfl_xor((int)cEF, 32);
        u32x4 b1w = hi ? u32x4{x45, x67, c45, c67} : u32x4{c01, c23, x01, x23};
        u32x4 b2w = hi ? u32x4{xCD, xEF, cCD, cEF} : u32x4{c89, cAB, x89, xAB};
        bf16x8 B1 = __builtin_bit_cast(bf16x8, b1w);
        bf16x8 B2 = __builtin_bit_cast(bf16x8, b2w);

        O = mfma32(vf1, B1, O);
        O = mfma32(vf2, B2, O);
    }

    float inv = 1.f / l;
    size_t orow;
    if constexpr (MODE == 0) {
        int b = s >> 7, f = s & 127;
        orow = ((size_t)(b * 256 + q)) * 128 + f;   // back to [B,T,F]
    } else {
        orow = (size_t)s * 128 + q;
    }
    bf16* op = o + orow * 128 + h * 32;
    #pragma unroll
    for (int mb = 0; mb < 4; ++mb) {
        bf16x4 ov;
        #pragma unroll
        for (int j = 0; j < 4; ++j) ov[j] = (bf16)(O[mb * 4 + j] * inv);
        *(bf16x4*)&op[mb * 8 + hi * 4] = ov;
    }
}

// ---------------------------------------------------------------------------
extern "C" void kernel_launch(void* const* d_in, const int* in_sizes, int n_in,
                              void* d_out, int out_size, void* d_ws, size_t ws_size,
                              hipStream_t stream) {
    const float* x      = (const float*)d_in[0];
    const float* ln_t_w = (const float*)d_in[1];
    const float* ln_t_b = (const float*)d_in[2];
    const float* t_wi   = (const float*)d_in[3];
    const float* t_bi   = (const float*)d_in[4];
    const float* t_wo   = (const float*)d_in[5];
    const float* t_bo   = (const float*)d_in[6];
    const float* ln_f_w = (const float*)d_in[7];
    const float* ln_f_b = (const float*)d_in[8];
    const float* f_wi   = (const float*)d_in[9];
    const float* f_bi   = (const float*)d_in[10];
    const float* f_wo   = (const float*)d_in[11];
    const float* f_bo   = (const float*)d_in[12];
    const float* ln_n_w = (const float*)d_in[13];
    const float* ln_n_b = (const float*)d_in[14];
    const float* w1     = (const float*)d_in[15];
    const float* b1     = (const float*)d_in[16];
    const float* w2     = (const float*)d_in[17];
    const float* b2     = (const float*)d_in[18];

    char* ws = (char*)d_ws;
    bf16* wbf  = (bf16*)ws;                                      // 512 KB
    bf16* xn   = (bf16*)(ws + 524288);                           // 16 MB
    bf16* qkvh = (bf16*)(ws + 524288 + 16777216);                // 64 MB (qkv / h)
    bf16* obf  = (bf16*)(ws + 524288 + 16777216 + 67108864);     // 16 MB
    float* xcur = (float*)(ws + 524288 + 16777216 + 67108864 + 16777216); // 32 MB
    float* out = (float*)d_out;

    const bf16* twi_b = wbf + 0;
    const bf16* two_b = wbf + 49152;
    const bf16* fwi_b = wbf + 65536;
    const bf16* fwo_b = wbf + 114688;
    const bf16* w1_b  = wbf + 131072;
    const bf16* w2_b  = wbf + 196608;

    // 0) weights -> bf16
    cvt_w6<<<256, 256, 0, stream>>>(t_wi, t_wo, f_wi, f_wo, w1, w2, wbf);

    // 1) temporal: LN (transposed write), QKV, attn (causal), out-proj+res (+fused ln_f)
    ln_t_k<<<16384, 256, 0, stream>>>(x, ln_t_w, ln_t_b, xn);
    gemm_rw<1, 0, 0, 0><<<dim3(1024, 3), 256, 0, stream>>>(
        xn, twi_b, t_bi, nullptr, qkvh, nullptr, nullptr, nullptr, 384, 128);
    attn_k<0><<<dim3(256, 4, 2), 256, 0, stream>>>(qkvh, obf);
    gemm_rw<0, 1, 0, 1><<<dim3(1024, 1), 256, 0, stream>>>(
        obf, two_b, t_bo, x, xcur, xn, ln_f_w, ln_f_b, 128, 128);

    // 2) frequency: QKV, attn (band), out-proj+res in-place (+fused ln_n)
    gemm_rw<1, 0, 0, 0><<<dim3(1024, 3), 256, 0, stream>>>(
        xn, fwi_b, f_bi, nullptr, qkvh, nullptr, nullptr, nullptr, 384, 128);
    attn_k<1><<<dim3(512, 4), 256, 0, stream>>>(qkvh, obf);
    gemm_rw<0, 1, 0, 1><<<dim3(1024, 1), 256, 0, stream>>>(
        obf, fwo_b, f_bo, xcur, xcur, xn, ln_n_w, ln_n_b, 128, 128);

    // 3) FFN: W1+GELU, W2+res -> d_out
    gemm_rw<1, 0, 1, 0><<<dim3(1024, 4), 256, 0, stream>>>(
        xn, w1_b, b1, nullptr, qkvh, nullptr, nullptr, nullptr, 512, 128);
    gemm_rw<0, 1, 0, 0><<<dim3(1024, 1), 256, 0, stream>>>(
        qkvh, w2_b, b2, xcur, out, nullptr, nullptr, nullptr, 128, 512);

    (void)in_sizes; (void)n_in; (void)out_size; (void)ws_size;
}

// Round 4
// 188.621 us; speedup vs baseline: 1.3480x; 1.0612x over previous
//
#include <hip/hip_runtime.h>
#include <math.h>

typedef __bf16 bf16;
typedef __bf16 bf16x8 __attribute__((ext_vector_type(8)));
typedef __bf16 bf16x4 __attribute__((ext_vector_type(4)));
typedef __bf16 bf16x2 __attribute__((ext_vector_type(2)));
typedef float f32x4 __attribute__((ext_vector_type(4)));
typedef float f32x2 __attribute__((ext_vector_type(2)));
typedef float f32x16 __attribute__((ext_vector_type(16)));
typedef unsigned int u32;
typedef unsigned int u32x4 __attribute__((ext_vector_type(4)));

#define AS1 __attribute__((address_space(1)))
#define AS3 __attribute__((address_space(3)))

static __device__ __forceinline__ f32x4 mfma16(bf16x8 a, bf16x8 b, f32x4 c) {
    return __builtin_amdgcn_mfma_f32_16x16x32_bf16(a, b, c, 0, 0, 0);
}
static __device__ __forceinline__ f32x16 mfma32(bf16x8 a, bf16x8 b, f32x16 c) {
    return __builtin_amdgcn_mfma_f32_32x32x16_bf16(a, b, c, 0, 0, 0);
}
static __device__ __forceinline__ u32 pk2(float a, float b) {
    bf16x2 v; v[0] = (bf16)a; v[1] = (bf16)b;
    return __builtin_bit_cast(u32, v);
}
// fast GELU (tanh form): gelu(x) = x - x / (exp(2u)+1), u = c*x*(1+0.044715 x^2)
// max |err| vs exact-erf gelu ~5e-4, far below bf16 rounding of h.
static __device__ __forceinline__ float gelu_f(float x) {
    float u = 0.7978845608f * x * __builtin_fmaf(0.044715f, x * x, 1.0f);
    float e = __expf(2.0f * u);
    return x - x * __builtin_amdgcn_rcpf(e + 1.0f);
}

// ---------------------------------------------------------------------------
// Convert the six weight matrices f32 -> bf16 into one packed ws region.
// ---------------------------------------------------------------------------
__global__ __launch_bounds__(256) void cvt_w6(
    const float* __restrict__ s0, const float* __restrict__ s1,
    const float* __restrict__ s2, const float* __restrict__ s3,
    const float* __restrict__ s4, const float* __restrict__ s5,
    bf16* __restrict__ dst)
{
    int i = (blockIdx.x * 256 + threadIdx.x) * 4;
    const float* src; int off;
    if      (i <  49152) { src = s0; off = 0; }
    else if (i <  65536) { src = s1; off = 49152; }
    else if (i < 114688) { src = s2; off = 65536; }
    else if (i < 131072) { src = s3; off = 114688; }
    else if (i < 196608) { src = s4; off = 131072; }
    else                 { src = s5; off = 196608; }
    f32x4 v = *(const f32x4*)&src[i - off];
    bf16x4 b;
    b[0] = (bf16)v[0]; b[1] = (bf16)v[1]; b[2] = (bf16)v[2]; b[3] = (bf16)v[3];
    *(bf16x4*)&dst[i] = b;
}

// ---------------------------------------------------------------------------
// Row-wave GEMM: out[M,N] = epi(A[M,K] @ W[N,K]^T + bias (+res))
// Block = 64 rows x 128 cols, 4 waves; each wave owns 16 FULL rows.
// A-frags straight from global to regs (no LDS); W staged via global_load_lds
// with XOR bank swizzle (pre-swizzled source + swizzled ds_read).
// LNF=1 (N==128): fused LayerNorm epilogue -> xnout (bf16); main out gets the
// pre-LN residual value.
// LNA=1 (KT==128): A = LayerNorm(x) computed on the fly from f32 x in
// [B,T,F,C] layout, with the [B,T,F]->[B,F,T] row remap folded in.
// ---------------------------------------------------------------------------
template<int OUT_BF16, int RES, int GELU_, int LNF, int LNA, int KT>
__global__ __launch_bounds__(256) void gemm_rw(
    const bf16* __restrict__ A, const bf16* __restrict__ W,
    const float* __restrict__ bias, const float* __restrict__ res,
    void* __restrict__ outp, bf16* __restrict__ xnout,
    const float* __restrict__ lnw, const float* __restrict__ lnb,
    const float* __restrict__ xf, const float* __restrict__ lnaw,
    const float* __restrict__ lnab, int N)
{
    __shared__ __align__(16) bf16 Bs[128 * 64];
    const int tid  = threadIdx.x;
    const int lane = tid & 63;
    const int w    = tid >> 6;
    const int li = lane & 15, g = lane >> 4;
    const int m0 = blockIdx.x * 64;
    const int n0 = blockIdx.y * 128;
    const int arow = m0 + w * 16 + li;
    const bf16* ap = A + (size_t)arow * KT;

    bf16x8 afrag[4];
    if constexpr (LNA) {
        // arow is in [B,F,T] order; source x row is [B,T,F]
        int b = arow >> 15, f = (arow >> 8) & 127, t = arow & 255;
        const float* xp = xf + (((size_t)b * 256 + t) * 128 + f) * 128;
        f32x4 cv[8];
        #pragma unroll
        for (int cc = 0; cc < 4; ++cc) {
            cv[2 * cc]     = *(const f32x4*)&xp[cc * 32 + g * 8];
            cv[2 * cc + 1] = *(const f32x4*)&xp[cc * 32 + g * 8 + 4];
        }
        float sm = 0.f, sq = 0.f;
        #pragma unroll
        for (int i = 0; i < 8; ++i)
            #pragma unroll
            for (int j = 0; j < 4; ++j) { float v = cv[i][j]; sm += v; sq += v * v; }
        sm += __shfl_xor(sm, 16); sm += __shfl_xor(sm, 32);
        sq += __shfl_xor(sq, 16); sq += __shfl_xor(sq, 32);
        float mu = sm * 0.0078125f;
        float rs = rsqrtf(sq * 0.0078125f - mu * mu + 1e-5f);
        #pragma unroll
        for (int cc = 0; cc < 4; ++cc) {
            f32x4 w0 = *(const f32x4*)&lnaw[cc * 32 + g * 8];
            f32x4 w1 = *(const f32x4*)&lnaw[cc * 32 + g * 8 + 4];
            f32x4 b0 = *(const f32x4*)&lnab[cc * 32 + g * 8];
            f32x4 b1 = *(const f32x4*)&lnab[cc * 32 + g * 8 + 4];
            #pragma unroll
            for (int j = 0; j < 4; ++j) {
                afrag[cc][j]     = (bf16)((cv[2 * cc][j]     - mu) * rs * w0[j] + b0[j]);
                afrag[cc][4 + j] = (bf16)((cv[2 * cc + 1][j] - mu) * rs * w1[j] + b1[j]);
            }
        }
    }

    f32x4 acc[8] = {};

    #pragma unroll
    for (int k0 = 0; k0 < KT; k0 += 64) {
        #pragma unroll
        for (int it = 0; it < 4; ++it) {
            int idx = it * 256 + tid;
            int brow = idx >> 3, bch = idx & 7;
            const bf16* gp = W + (size_t)(n0 + brow) * KT + k0 + ((bch ^ (brow & 7)) * 8);
            __builtin_amdgcn_global_load_lds((AS1 void*)gp, (AS3 void*)(Bs + idx * 8), 16, 0, 0);
        }
        bf16x8 av0, av1;
        if constexpr (!LNA) {
            av0 = *(const bf16x8*)&ap[k0 + g * 8];
            av1 = *(const bf16x8*)&ap[k0 + 32 + g * 8];
        }
        __syncthreads();
        #pragma unroll
        for (int kk = 0; kk < 2; ++kk) {
            bf16x8 av;
            if constexpr (LNA) av = afrag[(k0 >> 5) + kk];
            else               av = kk ? av1 : av0;
            #pragma unroll
            for (int j = 0; j < 8; ++j) {
                int brow = j * 16 + li;
                int bch = (kk * 4 + g) ^ (li & 7);
                bf16x8 bv = *(const bf16x8*)&Bs[brow * 64 + bch * 8];
                acc[j] = mfma16(av, bv, acc[j]);
            }
        }
        __syncthreads();
    }

    float bcol[8], lw[8], lb[8];
    #pragma unroll
    for (int j = 0; j < 8; ++j) {
        bcol[j] = bias[n0 + j * 16 + li];
        if constexpr (LNF) { lw[j] = lnw[j * 16 + li]; lb[j] = lnb[j * 16 + li]; }
    }

    const int row0 = m0 + w * 16 + g * 4;
    #pragma unroll
    for (int r = 0; r < 4; ++r) {
        int row = row0 + r;
        float vals[8];
        #pragma unroll
        for (int j = 0; j < 8; ++j) {
            float v = acc[j][r] + bcol[j];
            if constexpr (RES) v += res[(size_t)row * N + n0 + j * 16 + li];
            if constexpr (GELU_) v = gelu_f(v);
            vals[j] = v;
        }
        #pragma unroll
        for (int j = 0; j < 8; ++j) {
            size_t off = (size_t)row * N + n0 + j * 16 + li;
            if constexpr (OUT_BF16) ((bf16*)outp)[off] = (bf16)vals[j];
            else                    ((float*)outp)[off] = vals[j];
        }
        if constexpr (LNF) {
            float sm = 0.f, sq = 0.f;
            #pragma unroll
            for (int j = 0; j < 8; ++j) { sm += vals[j]; sq += vals[j] * vals[j]; }
            #pragma unroll
            for (int off = 1; off < 16; off <<= 1) {
                sm += __shfl_xor(sm, off);
                sq += __shfl_xor(sq, off);
            }
            float mu  = sm * 0.0078125f;
            float var = sq * 0.0078125f - mu * mu;
            float rs  = rsqrtf(var + 1e-5f);
            #pragma unroll
            for (int j = 0; j < 8; ++j)
                xnout[(size_t)row * 128 + j * 16 + li] =
                    (bf16)((vals[j] - mu) * rs * lw[j] + lb[j]);
        }
    }
}

// ---------------------------------------------------------------------------
// Flash attention, swapped-operand in-register form (no LDS).
// MODE 0: causal S=256, seqs [B,F], out rows in [B,T,F]. MODE 1: band +-16,
// S=128. One wave = 32 q rows x dh=32; lane owns q = lane&31.
// ---------------------------------------------------------------------------
template<int MODE>
__global__ __launch_bounds__(256) void attn_k(
    const bf16* __restrict__ qkv, bf16* __restrict__ o)
{
    constexpr int S = (MODE == 0) ? 256 : 128;
    const int lane = threadIdx.x & 63;
    const int w = threadIdx.x >> 6;
    const int hi = lane >> 5;
    const int q31 = lane & 31;
    const int s = blockIdx.x;
    const int h = blockIdx.y;
    const int qb = (MODE == 0) ? ((int)blockIdx.z * 128 + w * 32) : (w * 32);
    const int q = qb + q31;

    const size_t base = (size_t)s * S * 384;
    const bf16* qp = qkv + base + h * 32;
    const bf16* kp = qp + 128;
    const bf16* vp = qp + 256 + q31;

    bf16x8 qf0 = *(const bf16x8*)&qp[(size_t)q * 384 + hi * 8];
    bf16x8 qf1 = *(const bf16x8*)&qp[(size_t)q * 384 + 16 + hi * 8];

    f32x16 O = {};
    float m = -1e30f, l = 0.f;

    int klo, khi;
    if constexpr (MODE == 0) { klo = 0; khi = qb + 32; }
    else {
        klo = (qb > 16 ? (qb - 16) : 0) & ~31;
        khi = (qb + 48 < S) ? (qb + 48) : S;
    }

    const float sc = 0.17677669529663687f;  // 1/sqrt(32)

    for (int k0 = klo; k0 < khi; k0 += 32) {
        bf16x8 kf0 = *(const bf16x8*)&kp[(size_t)(k0 + q31) * 384 + hi * 8];
        bf16x8 kf1 = *(const bf16x8*)&kp[(size_t)(k0 + q31) * 384 + 16 + hi * 8];
        bf16x8 vf1, vf2;
        #pragma unroll
        for (int e = 0; e < 8; ++e) {
            vf1[e] = vp[(size_t)(k0 + hi * 8 + e) * 384];
            vf2[e] = vp[(size_t)(k0 + 16 + hi * 8 + e) * 384];
        }

        f32x16 st = {};
        st = mfma32(kf0, qf0, st);
        st = mfma32(kf1, qf1, st);

        float mx = -3.0e38f;
        #pragma unroll
        for (int r = 0; r < 16; ++r) {
            int krow = k0 + (r & 3) + 8 * (r >> 2) + 4 * hi;
            bool ok;
            if constexpr (MODE == 0) ok = (krow <= q);
            else { int d = krow - q; ok = (d <= 16 && d >= -16); }
            float v = ok ? st[r] * sc : -3.0e38f;
            st[r] = v;
            mx = fmaxf(mx, v);
        }
        mx = fmaxf(mx, __shfl_xor(mx, 32));
        float mn = fmaxf(m, mx);
        float resc = __expf(m - mn);
        m = mn;
        float ps = 0.f;
        #pragma unroll
        for (int r = 0; r < 16; ++r) {
            float p = __expf(st[r] - mn);
            st[r] = p;
            ps += p;
        }
        ps += __shfl_xor(ps, 32);
        l = l * resc + ps;
        #pragma unroll
        for (int r = 0; r < 16; ++r) O[r] *= resc;

        u32 c01 = pk2(st[0], st[1]),   c23 = pk2(st[2], st[3]);
        u32 c45 = pk2(st[4], st[5]),   c67 = pk2(st[6], st[7]);
        u32 c89 = pk2(st[8], st[9]),   cAB = pk2(st[10], st[11]);
        u32 cCD = pk2(st[12], st[13]), cEF = pk2(st[14], st[15]);
        u32 x01 = __shfl_xor((int)c01, 32), x23 = __shfl_xor((int)c23, 32);
        u32 x45 = __shfl_xor((int)c45, 32), x67 = __shfl_xor((int)c67, 32);
        u32 x89 = __shfl_xor((int)c89, 32), xAB = __shfl_xor((int)cAB, 32);
        u32 xCD = __shfl_xor((int)cCD, 32), xEF = __shfl_xor((int)cEF, 32);
        u32x4 b1w = hi ? u32x4{x45, x67, c45, c67} : u32x4{c01, c23, x01, x23};
        u32x4 b2w = hi ? u32x4{xCD, xEF, cCD, cEF} : u32x4{c89, cAB, x89, xAB};
        bf16x8 B1 = __builtin_bit_cast(bf16x8, b1w);
        bf16x8 B2 = __builtin_bit_cast(bf16x8, b2w);

        O = mfma32(vf1, B1, O);
        O = mfma32(vf2, B2, O);
    }

    float inv = 1.f / l;
    size_t orow;
    if constexpr (MODE == 0) {
        int b = s >> 7, f = s & 127;
        orow = ((size_t)(b * 256 + q)) * 128 + f;   // back to [B,T,F]
    } else {
        orow = (size_t)s * 128 + q;
    }
    bf16* op = o + orow * 128 + h * 32;
    #pragma unroll
    for (int mb = 0; mb < 4; ++mb) {
        bf16x4 ov;
        #pragma unroll
        for (int j = 0; j < 4; ++j) ov[j] = (bf16)(O[mb * 4 + j] * inv);
        *(bf16x4*)&op[mb * 8 + hi * 4] = ov;
    }
}

// ---------------------------------------------------------------------------
extern "C" void kernel_launch(void* const* d_in, const int* in_sizes, int n_in,
                              void* d_out, int out_size, void* d_ws, size_t ws_size,
                              hipStream_t stream) {
    const float* x      = (const float*)d_in[0];
    const float* ln_t_w = (const float*)d_in[1];
    const float* ln_t_b = (const float*)d_in[2];
    const float* t_wi   = (const float*)d_in[3];
    const float* t_bi   = (const float*)d_in[4];
    const float* t_wo   = (const float*)d_in[5];
    const float* t_bo   = (const float*)d_in[6];
    const float* ln_f_w = (const float*)d_in[7];
    const float* ln_f_b = (const float*)d_in[8];
    const float* f_wi   = (const float*)d_in[9];
    const float* f_bi   = (const float*)d_in[10];
    const float* f_wo   = (const float*)d_in[11];
    const float* f_bo   = (const float*)d_in[12];
    const float* ln_n_w = (const float*)d_in[13];
    const float* ln_n_b = (const float*)d_in[14];
    const float* w1     = (const float*)d_in[15];
    const float* b1     = (const float*)d_in[16];
    const float* w2     = (const float*)d_in[17];
    const float* b2     = (const float*)d_in[18];

    char* ws = (char*)d_ws;
    bf16* wbf  = (bf16*)ws;                                      // 512 KB
    bf16* xn   = (bf16*)(ws + 524288);                           // 16 MB
    bf16* qkvh = (bf16*)(ws + 524288 + 16777216);                // 64 MB (qkv / h)
    bf16* obf  = (bf16*)(ws + 524288 + 16777216 + 67108864);     // 16 MB
    float* xcur = (float*)(ws + 524288 + 16777216 + 67108864 + 16777216); // 32 MB
    float* out = (float*)d_out;

    const bf16* twi_b = wbf + 0;
    const bf16* two_b = wbf + 49152;
    const bf16* fwi_b = wbf + 65536;
    const bf16* fwo_b = wbf + 114688;
    const bf16* w1_b  = wbf + 131072;
    const bf16* w2_b  = wbf + 196608;

    // 0) weights -> bf16
    cvt_w6<<<256, 256, 0, stream>>>(t_wi, t_wo, f_wi, f_wo, w1, w2, wbf);

    // 1) temporal: QKV (fused ln_t from f32 x), attn (causal), out-proj+res (+fused ln_f)
    gemm_rw<1, 0, 0, 0, 1, 128><<<dim3(1024, 3), 256, 0, stream>>>(
        nullptr, twi_b, t_bi, nullptr, qkvh, nullptr, nullptr, nullptr,
        x, ln_t_w, ln_t_b, 384);
    attn_k<0><<<dim3(256, 4, 2), 256, 0, stream>>>(qkvh, obf);
    gemm_rw<0, 1, 0, 1, 0, 128><<<dim3(1024, 1), 256, 0, stream>>>(
        obf, two_b, t_bo, x, xcur, xn, ln_f_w, ln_f_b, nullptr, nullptr, nullptr, 128);

    // 2) frequency: QKV, attn (band), out-proj+res in-place (+fused ln_n)
    gemm_rw<1, 0, 0, 0, 0, 128><<<dim3(1024, 3), 256, 0, stream>>>(
        xn, fwi_b, f_bi, nullptr, qkvh, nullptr, nullptr, nullptr,
        nullptr, nullptr, nullptr, 384);
    attn_k<1><<<dim3(512, 4), 256, 0, stream>>>(qkvh, obf);
    gemm_rw<0, 1, 0, 1, 0, 128><<<dim3(1024, 1), 256, 0, stream>>>(
        obf, fwo_b, f_bo, xcur, xcur, xn, ln_n_w, ln_n_b, nullptr, nullptr, nullptr, 128);

    // 3) FFN: W1+GELU, W2+res -> d_out
    gemm_rw<1, 0, 1, 0, 0, 128><<<dim3(1024, 4), 256, 0, stream>>>(
        xn, w1_b, b1, nullptr, qkvh, nullptr, nullptr, nullptr,
        nullptr, nullptr, nullptr, 512);
    gemm_rw<0, 1, 0, 0, 0, 512><<<dim3(1024, 1), 256, 0, stream>>>(
        qkvh, w2_b, b2, xcur, out, nullptr, nullptr, nullptr,
        nullptr, nullptr, nullptr, 128);

    (void)in_sizes; (void)n_in; (void)out_size; (void)ws_size;
}

// Round 5
// 169.659 us; speedup vs baseline: 1.4987x; 1.1118x over previous
//
#include <hip/hip_runtime.h>
#include <math.h>

typedef __bf16 bf16;
typedef __bf16 bf16x8 __attribute__((ext_vector_type(8)));
typedef __bf16 bf16x4 __attribute__((ext_vector_type(4)));
typedef __bf16 bf16x2 __attribute__((ext_vector_type(2)));
typedef float f32x4 __attribute__((ext_vector_type(4)));
typedef float f32x2 __attribute__((ext_vector_type(2)));
typedef float f32x16 __attribute__((ext_vector_type(16)));
typedef unsigned int u32;
typedef unsigned int u32x4 __attribute__((ext_vector_type(4)));

#define AS1 __attribute__((address_space(1)))
#define AS3 __attribute__((address_space(3)))

static __device__ __forceinline__ f32x4 mfma16(bf16x8 a, bf16x8 b, f32x4 c) {
    return __builtin_amdgcn_mfma_f32_16x16x32_bf16(a, b, c, 0, 0, 0);
}
static __device__ __forceinline__ f32x16 mfma32(bf16x8 a, bf16x8 b, f32x16 c) {
    return __builtin_amdgcn_mfma_f32_32x32x16_bf16(a, b, c, 0, 0, 0);
}
static __device__ __forceinline__ u32 pk2(float a, float b) {
    bf16x2 v; v[0] = (bf16)a; v[1] = (bf16)b;
    return __builtin_bit_cast(u32, v);
}
// fast GELU (tanh form): max |err| vs exact-erf gelu ~5e-4.
static __device__ __forceinline__ float gelu_f(float x) {
    float u = 0.7978845608f * x * __builtin_fmaf(0.044715f, x * x, 1.0f);
    float e = __expf(2.0f * u);
    return x - x * __builtin_amdgcn_rcpf(e + 1.0f);
}

// ---------------------------------------------------------------------------
// Convert the six weight matrices f32 -> bf16 into one packed ws region.
// ---------------------------------------------------------------------------
__global__ __launch_bounds__(256) void cvt_w6(
    const float* __restrict__ s0, const float* __restrict__ s1,
    const float* __restrict__ s2, const float* __restrict__ s3,
    const float* __restrict__ s4, const float* __restrict__ s5,
    bf16* __restrict__ dst)
{
    int i = (blockIdx.x * 256 + threadIdx.x) * 4;
    const float* src; int off;
    if      (i <  49152) { src = s0; off = 0; }
    else if (i <  65536) { src = s1; off = 49152; }
    else if (i < 114688) { src = s2; off = 65536; }
    else if (i < 131072) { src = s3; off = 114688; }
    else if (i < 196608) { src = s4; off = 131072; }
    else                 { src = s5; off = 196608; }
    f32x4 v = *(const f32x4*)&src[i - off];
    bf16x4 b;
    b[0] = (bf16)v[0]; b[1] = (bf16)v[1]; b[2] = (bf16)v[2]; b[3] = (bf16)v[3];
    *(bf16x4*)&dst[i] = b;
}

// ---------------------------------------------------------------------------
// Row-wave GEMM: out[M, NT*128] = epi(A[M,KT] @ W[NT*128,KT]^T + bias (+res))
// Block = 64 rows, 4 waves; each wave owns 16 FULL rows. NT column tiles are
// looped IN-kernel so A (and the fused input-LN) is read/computed once.
// A-frags live in registers for KT=128 (no A-LDS); W staged via
// global_load_lds with XOR bank swizzle (pre-swizzled source, swizzled read).
// LNF=1 (NT==1): fused LayerNorm epilogue -> xnout (bf16); main out gets the
// pre-LN residual value. LNA=1 (KT==128): A = LayerNorm(xf) on the fly, with
// the [B,T,F]->[B,F,T] row remap folded into the source address.
// RESBF: residual input dtype (1 = bf16, 0 = f32).
// ---------------------------------------------------------------------------
template<int OUT_BF16, int RES, int RESBF, int GELU_, int LNF, int LNA, int KT, int NT>
__global__ __launch_bounds__(256) void gemm_rw(
    const bf16* __restrict__ A, const bf16* __restrict__ W,
    const float* __restrict__ bias, const void* __restrict__ res,
    void* __restrict__ outp, bf16* __restrict__ xnout,
    const float* __restrict__ lnw, const float* __restrict__ lnb,
    const float* __restrict__ xf, const float* __restrict__ lnaw,
    const float* __restrict__ lnab)
{
    constexpr int N = NT * 128;
    __shared__ __align__(16) bf16 Bs[128 * 64];
    const int tid  = threadIdx.x;
    const int lane = tid & 63;
    const int w    = tid >> 6;
    const int li = lane & 15, g = lane >> 4;
    const int m0 = blockIdx.x * 64;
    const int arow = m0 + w * 16 + li;
    const bf16* ap = A + (size_t)arow * KT;

    bf16x8 afrag[4];
    if constexpr (LNA) {
        // arow is in [B,F,T] order; source x row is [B,T,F]
        int b = arow >> 15, f = (arow >> 8) & 127, t = arow & 255;
        const float* xp = xf + (((size_t)b * 256 + t) * 128 + f) * 128;
        f32x4 cv[8];
        #pragma unroll
        for (int cc = 0; cc < 4; ++cc) {
            cv[2 * cc]     = *(const f32x4*)&xp[cc * 32 + g * 8];
            cv[2 * cc + 1] = *(const f32x4*)&xp[cc * 32 + g * 8 + 4];
        }
        float sm = 0.f, sq = 0.f;
        #pragma unroll
        for (int i = 0; i < 8; ++i)
            #pragma unroll
            for (int j = 0; j < 4; ++j) { float v = cv[i][j]; sm += v; sq += v * v; }
        sm += __shfl_xor(sm, 16); sm += __shfl_xor(sm, 32);
        sq += __shfl_xor(sq, 16); sq += __shfl_xor(sq, 32);
        float mu = sm * 0.0078125f;
        float rs = rsqrtf(sq * 0.0078125f - mu * mu + 1e-5f);
        #pragma unroll
        for (int cc = 0; cc < 4; ++cc) {
            f32x4 w0 = *(const f32x4*)&lnaw[cc * 32 + g * 8];
            f32x4 w1 = *(const f32x4*)&lnaw[cc * 32 + g * 8 + 4];
            f32x4 b0 = *(const f32x4*)&lnab[cc * 32 + g * 8];
            f32x4 b1 = *(const f32x4*)&lnab[cc * 32 + g * 8 + 4];
            #pragma unroll
            for (int j = 0; j < 4; ++j) {
                afrag[cc][j]     = (bf16)((cv[2 * cc][j]     - mu) * rs * w0[j] + b0[j]);
                afrag[cc][4 + j] = (bf16)((cv[2 * cc + 1][j] - mu) * rs * w1[j] + b1[j]);
            }
        }
    } else if constexpr (KT == 128) {
        #pragma unroll
        for (int cc = 0; cc < 4; ++cc)
            afrag[cc] = *(const bf16x8*)&ap[cc * 32 + g * 8];
    }

    #pragma unroll
    for (int t = 0; t < NT; ++t) {
        const int n0 = t * 128;
        f32x4 acc[8] = {};

        #pragma unroll
        for (int k0 = 0; k0 < KT; k0 += 64) {
            #pragma unroll
            for (int it = 0; it < 4; ++it) {
                int idx = it * 256 + tid;
                int brow = idx >> 3, bch = idx & 7;
                const bf16* gp = W + (size_t)(n0 + brow) * KT + k0 + ((bch ^ (brow & 7)) * 8);
                __builtin_amdgcn_global_load_lds((AS1 void*)gp, (AS3 void*)(Bs + idx * 8), 16, 0, 0);
            }
            bf16x8 av0, av1;
            if constexpr (KT != 128) {
                av0 = *(const bf16x8*)&ap[k0 + g * 8];
                av1 = *(const bf16x8*)&ap[k0 + 32 + g * 8];
            }
            __syncthreads();
            #pragma unroll
            for (int kk = 0; kk < 2; ++kk) {
                bf16x8 av;
                if constexpr (KT == 128) av = afrag[(k0 >> 5) + kk];
                else                     av = kk ? av1 : av0;
                #pragma unroll
                for (int j = 0; j < 8; ++j) {
                    int brow = j * 16 + li;
                    int bch = (kk * 4 + g) ^ (li & 7);
                    bf16x8 bv = *(const bf16x8*)&Bs[brow * 64 + bch * 8];
                    acc[j] = mfma16(av, bv, acc[j]);
                }
            }
            __syncthreads();
        }

        float bcol[8], lw[8], lb[8];
        #pragma unroll
        for (int j = 0; j < 8; ++j) {
            bcol[j] = bias[n0 + j * 16 + li];
            if constexpr (LNF) { lw[j] = lnw[j * 16 + li]; lb[j] = lnb[j * 16 + li]; }
        }

        const int row0 = m0 + w * 16 + g * 4;
        #pragma unroll
        for (int r = 0; r < 4; ++r) {
            int row = row0 + r;
            float vals[8];
            #pragma unroll
            for (int j = 0; j < 8; ++j) {
                float v = acc[j][r] + bcol[j];
                if constexpr (RES) {
                    size_t off = (size_t)row * N + n0 + j * 16 + li;
                    if constexpr (RESBF) v += (float)((const bf16*)res)[off];
                    else                 v += ((const float*)res)[off];
                }
                if constexpr (GELU_) v = gelu_f(v);
                vals[j] = v;
            }
            #pragma unroll
            for (int j = 0; j < 8; ++j) {
                size_t off = (size_t)row * N + n0 + j * 16 + li;
                if constexpr (OUT_BF16) ((bf16*)outp)[off] = (bf16)vals[j];
                else                    ((float*)outp)[off] = vals[j];
            }
            if constexpr (LNF) {
                float sm = 0.f, sq = 0.f;
                #pragma unroll
                for (int j = 0; j < 8; ++j) { sm += vals[j]; sq += vals[j] * vals[j]; }
                #pragma unroll
                for (int off = 1; off < 16; off <<= 1) {
                    sm += __shfl_xor(sm, off);
                    sq += __shfl_xor(sq, off);
                }
                float mu  = sm * 0.0078125f;
                float var = sq * 0.0078125f - mu * mu;
                float rs  = rsqrtf(var + 1e-5f);
                #pragma unroll
                for (int j = 0; j < 8; ++j)
                    xnout[(size_t)row * 128 + j * 16 + li] =
                        (bf16)((vals[j] - mu) * rs * lw[j] + lb[j]);
            }
        }
    }
}

// ---------------------------------------------------------------------------
// Flash attention, swapped-operand in-register form (no LDS).
// MODE 0: causal S=256, seqs [B,F], out rows in [B,T,F]. MODE 1: band +-16,
// S=128. One wave = 32 q rows x dh=32; lane owns q = lane&31.
// ---------------------------------------------------------------------------
template<int MODE>
__global__ __launch_bounds__(256) void attn_k(
    const bf16* __restrict__ qkv, bf16* __restrict__ o)
{
    constexpr int S = (MODE == 0) ? 256 : 128;
    const int lane = threadIdx.x & 63;
    const int w = threadIdx.x >> 6;
    const int hi = lane >> 5;
    const int q31 = lane & 31;
    const int s = blockIdx.x;
    const int h = blockIdx.y;
    const int qb = (MODE == 0) ? ((int)blockIdx.z * 128 + w * 32) : (w * 32);
    const int q = qb + q31;

    const size_t base = (size_t)s * S * 384;
    const bf16* qp = qkv + base + h * 32;
    const bf16* kp = qp + 128;
    const bf16* vp = qp + 256 + q31;

    bf16x8 qf0 = *(const bf16x8*)&qp[(size_t)q * 384 + hi * 8];
    bf16x8 qf1 = *(const bf16x8*)&qp[(size_t)q * 384 + 16 + hi * 8];

    f32x16 O = {};
    float m = -1e30f, l = 0.f;

    int klo, khi;
    if constexpr (MODE == 0) { klo = 0; khi = qb + 32; }
    else {
        klo = (qb > 16 ? (qb - 16) : 0) & ~31;
        khi = (qb + 48 < S) ? (qb + 48) : S;
    }

    const float sc = 0.17677669529663687f;  // 1/sqrt(32)

    for (int k0 = klo; k0 < khi; k0 += 32) {
        bf16x8 kf0 = *(const bf16x8*)&kp[(size_t)(k0 + q31) * 384 + hi * 8];
        bf16x8 kf1 = *(const bf16x8*)&kp[(size_t)(k0 + q31) * 384 + 16 + hi * 8];
        bf16x8 vf1, vf2;
        #pragma unroll
        for (int e = 0; e < 8; ++e) {
            vf1[e] = vp[(size_t)(k0 + hi * 8 + e) * 384];
            vf2[e] = vp[(size_t)(k0 + 16 + hi * 8 + e) * 384];
        }

        f32x16 st = {};
        st = mfma32(kf0, qf0, st);
        st = mfma32(kf1, qf1, st);

        float mx = -3.0e38f;
        #pragma unroll
        for (int r = 0; r < 16; ++r) {
            int krow = k0 + (r & 3) + 8 * (r >> 2) + 4 * hi;
            bool ok;
            if constexpr (MODE == 0) ok = (krow <= q);
            else { int d = krow - q; ok = (d <= 16 && d >= -16); }
            float v = ok ? st[r] * sc : -3.0e38f;
            st[r] = v;
            mx = fmaxf(mx, v);
        }
        mx = fmaxf(mx, __shfl_xor(mx, 32));
        float mn = fmaxf(m, mx);
        float resc = __expf(m - mn);
        m = mn;
        float ps = 0.f;
        #pragma unroll
        for (int r = 0; r < 16; ++r) {
            float p = __expf(st[r] - mn);
            st[r] = p;
            ps += p;
        }
        ps += __shfl_xor(ps, 32);
        l = l * resc + ps;
        #pragma unroll
        for (int r = 0; r < 16; ++r) O[r] *= resc;

        u32 c01 = pk2(st[0], st[1]),   c23 = pk2(st[2], st[3]);
        u32 c45 = pk2(st[4], st[5]),   c67 = pk2(st[6], st[7]);
        u32 c89 = pk2(st[8], st[9]),   cAB = pk2(st[10], st[11]);
        u32 cCD = pk2(st[12], st[13]), cEF = pk2(st[14], st[15]);
        u32 x01 = __shfl_xor((int)c01, 32), x23 = __shfl_xor((int)c23, 32);
        u32 x45 = __shfl_xor((int)c45, 32), x67 = __shfl_xor((int)c67, 32);
        u32 x89 = __shfl_xor((int)c89, 32), xAB = __shfl_xor((int)cAB, 32);
        u32 xCD = __shfl_xor((int)cCD, 32), xEF = __shfl_xor((int)cEF, 32);
        u32x4 b1w = hi ? u32x4{x45, x67, c45, c67} : u32x4{c01, c23, x01, x23};
        u32x4 b2w = hi ? u32x4{xCD, xEF, cCD, cEF} : u32x4{c89, cAB, x89, xAB};
        bf16x8 B1 = __builtin_bit_cast(bf16x8, b1w);
        bf16x8 B2 = __builtin_bit_cast(bf16x8, b2w);

        O = mfma32(vf1, B1, O);
        O = mfma32(vf2, B2, O);
    }

    float inv = 1.f / l;
    size_t orow;
    if constexpr (MODE == 0) {
        int b = s >> 7, f = s & 127;
        orow = ((size_t)(b * 256 + q)) * 128 + f;   // back to [B,T,F]
    } else {
        orow = (size_t)s * 128 + q;
    }
    bf16* op = o + orow * 128 + h * 32;
    #pragma unroll
    for (int mb = 0; mb < 4; ++mb) {
        bf16x4 ov;
        #pragma unroll
        for (int j = 0; j < 4; ++j) ov[j] = (bf16)(O[mb * 4 + j] * inv);
        *(bf16x4*)&op[mb * 8 + hi * 4] = ov;
    }
}

// ---------------------------------------------------------------------------
extern "C" void kernel_launch(void* const* d_in, const int* in_sizes, int n_in,
                              void* d_out, int out_size, void* d_ws, size_t ws_size,
                              hipStream_t stream) {
    const float* x      = (const float*)d_in[0];
    const float* ln_t_w = (const float*)d_in[1];
    const float* ln_t_b = (const float*)d_in[2];
    const float* t_wi   = (const float*)d_in[3];
    const float* t_bi   = (const float*)d_in[4];
    const float* t_wo   = (const float*)d_in[5];
    const float* t_bo   = (const float*)d_in[6];
    const float* ln_f_w = (const float*)d_in[7];
    const float* ln_f_b = (const float*)d_in[8];
    const float* f_wi   = (const float*)d_in[9];
    const float* f_bi   = (const float*)d_in[10];
    const float* f_wo   = (const float*)d_in[11];
    const float* f_bo   = (const float*)d_in[12];
    const float* ln_n_w = (const float*)d_in[13];
    const float* ln_n_b = (const float*)d_in[14];
    const float* w1     = (const float*)d_in[15];
    const float* b1     = (const float*)d_in[16];
    const float* w2     = (const float*)d_in[17];
    const float* b2     = (const float*)d_in[18];

    char* ws = (char*)d_ws;
    bf16* wbf  = (bf16*)ws;                                      // 512 KB
    bf16* xn   = (bf16*)(ws + 524288);                           // 16 MB
    bf16* qkvh = (bf16*)(ws + 524288 + 16777216);                // 64 MB (qkv / h)
    bf16* obf  = (bf16*)(ws + 524288 + 16777216 + 67108864);     // 16 MB
    bf16* xcA  = (bf16*)(ws + 524288 + 16777216 + 67108864 + 16777216);  // 16 MB
    bf16* xcB  = (bf16*)(ws + 524288 + 16777216 + 67108864 + 2 * 16777216); // 16 MB
    float* out = (float*)d_out;

    const bf16* twi_b = wbf + 0;
    const bf16* two_b = wbf + 49152;
    const bf16* fwi_b = wbf + 65536;
    const bf16* fwo_b = wbf + 114688;
    const bf16* w1_b  = wbf + 131072;
    const bf16* w2_b  = wbf + 196608;

    // 0) weights -> bf16
    cvt_w6<<<256, 256, 0, stream>>>(t_wi, t_wo, f_wi, f_wo, w1, w2, wbf);

    // 1) temporal: QKV (fused ln_t from f32 x, all 3 N-tiles in-kernel),
    //    attn (causal), out-proj + f32 x residual -> bf16 xcA (+fused ln_f)
    gemm_rw<1, 0, 0, 0, 0, 1, 128, 3><<<1024, 256, 0, stream>>>(
        nullptr, twi_b, t_bi, nullptr, qkvh, nullptr, nullptr, nullptr,
        x, ln_t_w, ln_t_b);
    attn_k<0><<<dim3(256, 4, 2), 256, 0, stream>>>(qkvh, obf);
    gemm_rw<1, 1, 0, 0, 1, 0, 128, 1><<<1024, 256, 0, stream>>>(
        obf, two_b, t_bo, x, xcA, xn, ln_f_w, ln_f_b, nullptr, nullptr, nullptr);

    // 2) frequency: QKV, attn (band), out-proj + bf16 residual -> xcB (+fused ln_n)
    gemm_rw<1, 0, 0, 0, 0, 0, 128, 3><<<1024, 256, 0, stream>>>(
        xn, fwi_b, f_bi, nullptr, qkvh, nullptr, nullptr, nullptr,
        nullptr, nullptr, nullptr);
    attn_k<1><<<dim3(512, 4), 256, 0, stream>>>(qkvh, obf);
    gemm_rw<1, 1, 1, 0, 1, 0, 128, 1><<<1024, 256, 0, stream>>>(
        obf, fwo_b, f_bo, xcA, xcB, xn, ln_n_w, ln_n_b, nullptr, nullptr, nullptr);

    // 3) FFN: W1+GELU (all 4 N-tiles in-kernel), W2 + bf16 residual -> f32 d_out
    gemm_rw<1, 0, 0, 1, 0, 0, 128, 4><<<1024, 256, 0, stream>>>(
        xn, w1_b, b1, nullptr, qkvh, nullptr, nullptr, nullptr,
        nullptr, nullptr, nullptr);
    gemm_rw<0, 1, 1, 0, 0, 0, 512, 1><<<1024, 256, 0, stream>>>(
        qkvh, w2_b, b2, xcB, out, nullptr, nullptr, nullptr,
        nullptr, nullptr, nullptr);

    (void)in_sizes; (void)n_in; (void)out_size; (void)ws_size;
}

// Round 6
// 165.873 us; speedup vs baseline: 1.5329x; 1.0228x over previous
//
#include <hip/hip_runtime.h>
#include <math.h>

typedef __bf16 bf16;
typedef __bf16 bf16x8 __attribute__((ext_vector_type(8)));
typedef __bf16 bf16x4 __attribute__((ext_vector_type(4)));
typedef __bf16 bf16x2 __attribute__((ext_vector_type(2)));
typedef float f32x4 __attribute__((ext_vector_type(4)));
typedef float f32x2 __attribute__((ext_vector_type(2)));
typedef float f32x16 __attribute__((ext_vector_type(16)));
typedef unsigned int u32;
typedef unsigned int u32x4 __attribute__((ext_vector_type(4)));

#define AS1 __attribute__((address_space(1)))
#define AS3 __attribute__((address_space(3)))

static __device__ __forceinline__ f32x4 mfma16(bf16x8 a, bf16x8 b, f32x4 c) {
    return __builtin_amdgcn_mfma_f32_16x16x32_bf16(a, b, c, 0, 0, 0);
}
static __device__ __forceinline__ f32x16 mfma32(bf16x8 a, bf16x8 b, f32x16 c) {
    return __builtin_amdgcn_mfma_f32_32x32x16_bf16(a, b, c, 0, 0, 0);
}
static __device__ __forceinline__ u32 pk2(float a, float b) {
    bf16x2 v; v[0] = (bf16)a; v[1] = (bf16)b;
    return __builtin_bit_cast(u32, v);
}
// fast GELU (tanh form): max |err| vs exact-erf gelu ~5e-4.
static __device__ __forceinline__ float gelu_f(float x) {
    float u = 0.7978845608f * x * __builtin_fmaf(0.044715f, x * x, 1.0f);
    float e = __expf(2.0f * u);
    return x - x * __builtin_amdgcn_rcpf(e + 1.0f);
}

// ---------------------------------------------------------------------------
// Convert the six weight matrices f32 -> bf16 into one packed ws region.
// ---------------------------------------------------------------------------
__global__ __launch_bounds__(256) void cvt_w6(
    const float* __restrict__ s0, const float* __restrict__ s1,
    const float* __restrict__ s2, const float* __restrict__ s3,
    const float* __restrict__ s4, const float* __restrict__ s5,
    bf16* __restrict__ dst)
{
    int i = (blockIdx.x * 256 + threadIdx.x) * 4;
    const float* src; int off;
    if      (i <  49152) { src = s0; off = 0; }
    else if (i <  65536) { src = s1; off = 49152; }
    else if (i < 114688) { src = s2; off = 65536; }
    else if (i < 131072) { src = s3; off = 114688; }
    else if (i < 196608) { src = s4; off = 131072; }
    else                 { src = s5; off = 196608; }
    f32x4 v = *(const f32x4*)&src[i - off];
    bf16x4 b;
    b[0] = (bf16)v[0]; b[1] = (bf16)v[1]; b[2] = (bf16)v[2]; b[3] = (bf16)v[3];
    *(bf16x4*)&dst[i] = b;
}

// ---------------------------------------------------------------------------
// Row-wave GEMM: out[M, NT*128] = epi(A[M,KT] @ W[NT*128,KT]^T + bias (+res))
// Block = 64 rows, 4 waves; each wave owns 16 FULL rows. NT column tiles
// looped in-kernel so A (and the fused input-LN) is read/computed once.
// LNA=1 (KT==128): A = LayerNorm(xf) on the fly, [B,T,F]->[B,F,T] remap
// folded into the source address. RESBF: residual dtype (1=bf16, 0=f32).
// ---------------------------------------------------------------------------
template<int OUT_BF16, int RES, int RESBF, int GELU_, int LNA, int KT, int NT>
__global__ __launch_bounds__(256) void gemm_rw(
    const bf16* __restrict__ A, const bf16* __restrict__ W,
    const float* __restrict__ bias, const void* __restrict__ res,
    void* __restrict__ outp,
    const float* __restrict__ xf, const float* __restrict__ lnaw,
    const float* __restrict__ lnab)
{
    constexpr int N = NT * 128;
    __shared__ __align__(16) bf16 Bs[128 * 64];
    const int tid  = threadIdx.x;
    const int lane = tid & 63;
    const int w    = tid >> 6;
    const int li = lane & 15, g = lane >> 4;
    const int m0 = blockIdx.x * 64;
    const int arow = m0 + w * 16 + li;
    const bf16* ap = A + (size_t)arow * KT;

    bf16x8 afrag[4];
    if constexpr (LNA) {
        // arow is in [B,F,T] order; source x row is [B,T,F]
        int b = arow >> 15, f = (arow >> 8) & 127, t = arow & 255;
        const float* xp = xf + (((size_t)b * 256 + t) * 128 + f) * 128;
        f32x4 cv[8];
        #pragma unroll
        for (int cc = 0; cc < 4; ++cc) {
            cv[2 * cc]     = *(const f32x4*)&xp[cc * 32 + g * 8];
            cv[2 * cc + 1] = *(const f32x4*)&xp[cc * 32 + g * 8 + 4];
        }
        float sm = 0.f, sq = 0.f;
        #pragma unroll
        for (int i = 0; i < 8; ++i)
            #pragma unroll
            for (int j = 0; j < 4; ++j) { float v = cv[i][j]; sm += v; sq += v * v; }
        sm += __shfl_xor(sm, 16); sm += __shfl_xor(sm, 32);
        sq += __shfl_xor(sq, 16); sq += __shfl_xor(sq, 32);
        float mu = sm * 0.0078125f;
        float rs = rsqrtf(sq * 0.0078125f - mu * mu + 1e-5f);
        #pragma unroll
        for (int cc = 0; cc < 4; ++cc) {
            f32x4 w0 = *(const f32x4*)&lnaw[cc * 32 + g * 8];
            f32x4 w1 = *(const f32x4*)&lnaw[cc * 32 + g * 8 + 4];
            f32x4 b0 = *(const f32x4*)&lnab[cc * 32 + g * 8];
            f32x4 b1 = *(const f32x4*)&lnab[cc * 32 + g * 8 + 4];
            #pragma unroll
            for (int j = 0; j < 4; ++j) {
                afrag[cc][j]     = (bf16)((cv[2 * cc][j]     - mu) * rs * w0[j] + b0[j]);
                afrag[cc][4 + j] = (bf16)((cv[2 * cc + 1][j] - mu) * rs * w1[j] + b1[j]);
            }
        }
    } else if constexpr (KT == 128) {
        #pragma unroll
        for (int cc = 0; cc < 4; ++cc)
            afrag[cc] = *(const bf16x8*)&ap[cc * 32 + g * 8];
    }

    #pragma unroll
    for (int t = 0; t < NT; ++t) {
        const int n0 = t * 128;
        f32x4 acc[8] = {};

        #pragma unroll
        for (int k0 = 0; k0 < KT; k0 += 64) {
            #pragma unroll
            for (int it = 0; it < 4; ++it) {
                int idx = it * 256 + tid;
                int brow = idx >> 3, bch = idx & 7;
                const bf16* gp = W + (size_t)(n0 + brow) * KT + k0 + ((bch ^ (brow & 7)) * 8);
                __builtin_amdgcn_global_load_lds((AS1 void*)gp, (AS3 void*)(Bs + idx * 8), 16, 0, 0);
            }
            bf16x8 av0, av1;
            if constexpr (KT != 128) {
                av0 = *(const bf16x8*)&ap[k0 + g * 8];
                av1 = *(const bf16x8*)&ap[k0 + 32 + g * 8];
            }
            __syncthreads();
            #pragma unroll
            for (int kk = 0; kk < 2; ++kk) {
                bf16x8 av;
                if constexpr (KT == 128) av = afrag[(k0 >> 5) + kk];
                else                     av = kk ? av1 : av0;
                #pragma unroll
                for (int j = 0; j < 8; ++j) {
                    int brow = j * 16 + li;
                    int bch = (kk * 4 + g) ^ (li & 7);
                    bf16x8 bv = *(const bf16x8*)&Bs[brow * 64 + bch * 8];
                    acc[j] = mfma16(av, bv, acc[j]);
                }
            }
            __syncthreads();
        }

        float bcol[8];
        #pragma unroll
        for (int j = 0; j < 8; ++j) bcol[j] = bias[n0 + j * 16 + li];

        const int row0 = m0 + w * 16 + g * 4;
        #pragma unroll
        for (int r = 0; r < 4; ++r) {
            int row = row0 + r;
            #pragma unroll
            for (int j = 0; j < 8; ++j) {
                size_t off = (size_t)row * N + n0 + j * 16 + li;
                float v = acc[j][r] + bcol[j];
                if constexpr (RES) {
                    if constexpr (RESBF) v += (float)((const bf16*)res)[off];
                    else                 v += ((const float*)res)[off];
                }
                if constexpr (GELU_) v = gelu_f(v);
                if constexpr (OUT_BF16) ((bf16*)outp)[off] = (bf16)v;
                else                    ((float*)outp)[off] = v;
            }
        }
    }
}

// ---------------------------------------------------------------------------
// Fused attention + out-projection + residual + LayerNorm.
// Block = 32 q-rows of one sequence; 4 waves = 4 heads (one head/wave).
// Flash attention (swapped-operand, in-register); normalized O staged into a
// padded 32x136 LDS tile; then the 4 waves do the 32x128x128 out-proj GEMM
// (W_o b-frags from L2), add bias + residual, cross-wave LDS reduce for LN,
// and write both the bf16 residual stream (xc) and the LN'd xn.
// MODE 0: causal S=256, seqs [B,F], rows scattered to [B,T,F] order.
// MODE 1: band |i-j|<=16, S=128, natural order. RESBF: residual dtype.
// ---------------------------------------------------------------------------
template<int MODE, int RESBF>
__global__ __launch_bounds__(256) void attn_fused(
    const bf16* __restrict__ qkv, const bf16* __restrict__ Wo,
    const float* __restrict__ bo, const void* __restrict__ res,
    bf16* __restrict__ xc, bf16* __restrict__ xn,
    const float* __restrict__ lnw, const float* __restrict__ lnb)
{
    constexpr int S = (MODE == 0) ? 256 : 128;
    __shared__ __align__(16) bf16 o_lds[32 * 136];
    __shared__ float red[32][4][2];
    const int lane = threadIdx.x & 63;
    const int w = threadIdx.x >> 6;     // wave = head
    const int hi = lane >> 5;
    const int q31 = lane & 31;
    const int s = blockIdx.x;
    const int qb = blockIdx.y * 32;
    const int q = qb + q31;

    const size_t base = (size_t)s * S * 384;
    const bf16* qp = qkv + base + w * 32;
    const bf16* kp = qp + 128;
    const bf16* vp = qp + 256 + q31;

    bf16x8 qf0 = *(const bf16x8*)&qp[(size_t)q * 384 + hi * 8];
    bf16x8 qf1 = *(const bf16x8*)&qp[(size_t)q * 384 + 16 + hi * 8];

    f32x16 O = {};
    float m = -1e30f, l = 0.f;

    int klo, khi;
    if constexpr (MODE == 0) { klo = 0; khi = qb + 32; }
    else {
        klo = (qb > 16 ? (qb - 16) : 0) & ~31;
        khi = (qb + 48 < S) ? (qb + 48) : S;
    }

    const float sc = 0.17677669529663687f;  // 1/sqrt(32)

    for (int k0 = klo; k0 < khi; k0 += 32) {
        bf16x8 kf0 = *(const bf16x8*)&kp[(size_t)(k0 + q31) * 384 + hi * 8];
        bf16x8 kf1 = *(const bf16x8*)&kp[(size_t)(k0 + q31) * 384 + 16 + hi * 8];
        bf16x8 vf1, vf2;
        #pragma unroll
        for (int e = 0; e < 8; ++e) {
            vf1[e] = vp[(size_t)(k0 + hi * 8 + e) * 384];
            vf2[e] = vp[(size_t)(k0 + 16 + hi * 8 + e) * 384];
        }

        f32x16 st = {};
        st = mfma32(kf0, qf0, st);
        st = mfma32(kf1, qf1, st);

        float mx = -3.0e38f;
        #pragma unroll
        for (int r = 0; r < 16; ++r) {
            int krow = k0 + (r & 3) + 8 * (r >> 2) + 4 * hi;
            bool ok;
            if constexpr (MODE == 0) ok = (krow <= q);
            else { int d = krow - q; ok = (d <= 16 && d >= -16); }
            float v = ok ? st[r] * sc : -3.0e38f;
            st[r] = v;
            mx = fmaxf(mx, v);
        }
        mx = fmaxf(mx, __shfl_xor(mx, 32));
        float mn = fmaxf(m, mx);
        float resc = __expf(m - mn);
        m = mn;
        float ps = 0.f;
        #pragma unroll
        for (int r = 0; r < 16; ++r) {
            float p = __expf(st[r] - mn);
            st[r] = p;
            ps += p;
        }
        ps += __shfl_xor(ps, 32);
        l = l * resc + ps;
        #pragma unroll
        for (int r = 0; r < 16; ++r) O[r] *= resc;

        u32 c01 = pk2(st[0], st[1]),   c23 = pk2(st[2], st[3]);
        u32 c45 = pk2(st[4], st[5]),   c67 = pk2(st[6], st[7]);
        u32 c89 = pk2(st[8], st[9]),   cAB = pk2(st[10], st[11]);
        u32 cCD = pk2(st[12], st[13]), cEF = pk2(st[14], st[15]);
        u32 x01 = __shfl_xor((int)c01, 32), x23 = __shfl_xor((int)c23, 32);
        u32 x45 = __shfl_xor((int)c45, 32), x67 = __shfl_xor((int)c67, 32);
        u32 x89 = __shfl_xor((int)c89, 32), xAB = __shfl_xor((int)cAB, 32);
        u32 xCD = __shfl_xor((int)cCD, 32), xEF = __shfl_xor((int)cEF, 32);
        u32x4 b1w = hi ? u32x4{x45, x67, c45, c67} : u32x4{c01, c23, x01, x23};
        u32x4 b2w = hi ? u32x4{xCD, xEF, cCD, cEF} : u32x4{c89, cAB, x89, xAB};
        bf16x8 B1 = __builtin_bit_cast(bf16x8, b1w);
        bf16x8 B2 = __builtin_bit_cast(bf16x8, b2w);

        O = mfma32(vf1, B1, O);
        O = mfma32(vf2, B2, O);
    }

    // stage normalized O into LDS: o_lds[q][w*32 + (mb*8 + hi*4 + j)]
    float inv = 1.f / l;
    #pragma unroll
    for (int mb = 0; mb < 4; ++mb) {
        bf16x4 ov;
        #pragma unroll
        for (int j = 0; j < 4; ++j) ov[j] = (bf16)(O[mb * 4 + j] * inv);
        *(bf16x4*)&o_lds[q31 * 136 + w * 32 + mb * 8 + hi * 4] = ov;
    }
    __syncthreads();

    // out-proj GEMM: M=32 (2 m-tiles), wave w owns N cols [w*32, w*32+32)
    const int li = lane & 15, g = lane >> 4;
    bf16x8 af[2][4];
    #pragma unroll
    for (int mi = 0; mi < 2; ++mi)
        #pragma unroll
        for (int kk = 0; kk < 4; ++kk)
            af[mi][kk] = *(const bf16x8*)&o_lds[(mi * 16 + li) * 136 + kk * 32 + g * 8];

    f32x4 acc[2][2] = {};
    #pragma unroll
    for (int ni = 0; ni < 2; ++ni) {
        #pragma unroll
        for (int kk = 0; kk < 4; ++kk) {
            bf16x8 bv = *(const bf16x8*)&Wo[(size_t)(w * 32 + ni * 16 + li) * 128 + kk * 32 + g * 8];
            acc[0][ni] = mfma16(af[0][kk], bv, acc[0][ni]);
            acc[1][ni] = mfma16(af[1][kk], bv, acc[1][ni]);
        }
    }

    // epilogue: bias + residual, cross-wave LN stats, write xc + xn
    int b0_ = 0, f0_ = 0;
    if constexpr (MODE == 0) { b0_ = s >> 7; f0_ = s & 127; }
    float vals[2][2][4];
    size_t groff[2][4];
    #pragma unroll
    for (int mi = 0; mi < 2; ++mi) {
        #pragma unroll
        for (int r = 0; r < 4; ++r) {
            int mrow = qb + mi * 16 + g * 4 + r;
            size_t orow;
            if constexpr (MODE == 0) orow = ((size_t)(b0_ * 256 + mrow)) * 128 + f0_;
            else                     orow = (size_t)s * 128 + mrow;
            groff[mi][r] = orow * 128;
            #pragma unroll
            for (int ni = 0; ni < 2; ++ni) {
                int col = w * 32 + ni * 16 + li;
                float v = acc[mi][ni][r] + bo[col];
                if constexpr (RESBF) v += (float)((const bf16*)res)[groff[mi][r] + col];
                else                 v += ((const float*)res)[groff[mi][r] + col];
                vals[mi][ni][r] = v;
            }
        }
    }
    #pragma unroll
    for (int mi = 0; mi < 2; ++mi) {
        #pragma unroll
        for (int r = 0; r < 4; ++r) {
            float sm = vals[mi][0][r] + vals[mi][1][r];
            float sq = vals[mi][0][r] * vals[mi][0][r] + vals[mi][1][r] * vals[mi][1][r];
            #pragma unroll
            for (int off = 1; off < 16; off <<= 1) {
                sm += __shfl_xor(sm, off);
                sq += __shfl_xor(sq, off);
            }
            if (li == 0) {
                red[mi * 16 + g * 4 + r][w][0] = sm;
                red[mi * 16 + g * 4 + r][w][1] = sq;
            }
        }
    }
    __syncthreads();
    #pragma unroll
    for (int mi = 0; mi < 2; ++mi) {
        #pragma unroll
        for (int r = 0; r < 4; ++r) {
            int mrow = mi * 16 + g * 4 + r;
            f32x4 p0 = *(const f32x4*)&red[mrow][0][0];
            f32x4 p1 = *(const f32x4*)&red[mrow][2][0];
            float smt = p0[0] + p0[2] + p1[0] + p1[2];
            float sqt = p0[1] + p0[3] + p1[1] + p1[3];
            float mu = smt * 0.0078125f;
            float rs = rsqrtf(sqt * 0.0078125f - mu * mu + 1e-5f);
            #pragma unroll
            for (int ni = 0; ni < 2; ++ni) {
                int col = w * 32 + ni * 16 + li;
                float v = vals[mi][ni][r];
                xc[groff[mi][r] + col] = (bf16)v;
                xn[groff[mi][r] + col] = (bf16)((v - mu) * rs * lnw[col] + lnb[col]);
            }
        }
    }
}

// ---------------------------------------------------------------------------
extern "C" void kernel_launch(void* const* d_in, const int* in_sizes, int n_in,
                              void* d_out, int out_size, void* d_ws, size_t ws_size,
                              hipStream_t stream) {
    const float* x      = (const float*)d_in[0];
    const float* ln_t_w = (const float*)d_in[1];
    const float* ln_t_b = (const float*)d_in[2];
    const float* t_wi   = (const float*)d_in[3];
    const float* t_bi   = (const float*)d_in[4];
    const float* t_wo   = (const float*)d_in[5];
    const float* t_bo   = (const float*)d_in[6];
    const float* ln_f_w = (const float*)d_in[7];
    const float* ln_f_b = (const float*)d_in[8];
    const float* f_wi   = (const float*)d_in[9];
    const float* f_bi   = (const float*)d_in[10];
    const float* f_wo   = (const float*)d_in[11];
    const float* f_bo   = (const float*)d_in[12];
    const float* ln_n_w = (const float*)d_in[13];
    const float* ln_n_b = (const float*)d_in[14];
    const float* w1     = (const float*)d_in[15];
    const float* b1     = (const float*)d_in[16];
    const float* w2     = (const float*)d_in[17];
    const float* b2     = (const float*)d_in[18];

    char* ws = (char*)d_ws;
    bf16* wbf  = (bf16*)ws;                                      // 512 KB
    bf16* xn   = (bf16*)(ws + 524288);                           // 16 MB
    bf16* qkvh = (bf16*)(ws + 524288 + 16777216);                // 64 MB (qkv / h)
    bf16* xcA  = (bf16*)(ws + 524288 + 16777216 + 67108864 + 16777216);  // 16 MB
    bf16* xcB  = (bf16*)(ws + 524288 + 16777216 + 67108864 + 2 * 16777216); // 16 MB
    float* out = (float*)d_out;

    const bf16* twi_b = wbf + 0;
    const bf16* two_b = wbf + 49152;
    const bf16* fwi_b = wbf + 65536;
    const bf16* fwo_b = wbf + 114688;
    const bf16* w1_b  = wbf + 131072;
    const bf16* w2_b  = wbf + 196608;

    // 0) weights -> bf16
    cvt_w6<<<256, 256, 0, stream>>>(t_wi, t_wo, f_wi, f_wo, w1, w2, wbf);

    // 1) temporal: QKV (fused ln_t from f32 x, 3 N-tiles in-kernel),
    //    fused attn(causal)+outproj+res(f32 x)+ln_f -> xcA, xn
    gemm_rw<1, 0, 0, 0, 1, 128, 3><<<1024, 256, 0, stream>>>(
        nullptr, twi_b, t_bi, nullptr, qkvh, x, ln_t_w, ln_t_b);
    attn_fused<0, 0><<<dim3(256, 8), 256, 0, stream>>>(
        qkvh, two_b, t_bo, x, xcA, xn, ln_f_w, ln_f_b);

    // 2) frequency: QKV, fused attn(band)+outproj+res(bf16 xcA)+ln_n -> xcB, xn
    gemm_rw<1, 0, 0, 0, 0, 128, 3><<<1024, 256, 0, stream>>>(
        xn, fwi_b, f_bi, nullptr, qkvh, nullptr, nullptr, nullptr);
    attn_fused<1, 1><<<dim3(512, 4), 256, 0, stream>>>(
        qkvh, fwo_b, f_bo, xcA, xcB, xn, ln_n_w, ln_n_b);

    // 3) FFN: W1+GELU (4 N-tiles in-kernel), W2 + bf16 residual -> f32 d_out
    gemm_rw<1, 0, 0, 1, 0, 128, 4><<<1024, 256, 0, stream>>>(
        xn, w1_b, b1, nullptr, qkvh, nullptr, nullptr, nullptr);
    gemm_rw<0, 1, 1, 0, 0, 512, 1><<<1024, 256, 0, stream>>>(
        qkvh, w2_b, b2, xcB, out, nullptr, nullptr, nullptr);

    (void)in_sizes; (void)n_in; (void)out_size; (void)ws_size;
}